// Round 1
// baseline (6881.123 us; speedup 1.0000x reference)
//
#include <hip/hip_runtime.h>
#include <hip/hip_bf16.h>
#include <math.h>

#define N_NODES 50000
#define N_EDGES 300000
#define IN_DIM 128
#define C 256
#define LAYERS 6
#define N_GRAPHS 256

// ---------------------------------------------------------------------------
// CSR build
// ---------------------------------------------------------------------------
__global__ void count_kernel(const int* __restrict__ ei, int* __restrict__ deg) {
    int e = blockIdx.x * blockDim.x + threadIdx.x;
    if (e < N_EDGES) atomicAdd(&deg[ei[N_EDGES + e]], 1);
}

__global__ void scan_kernel(const int* __restrict__ deg, int* __restrict__ row_ptr,
                            int* __restrict__ cursor) {
    __shared__ int buf[1024];
    __shared__ int carry_s;
    int tid = threadIdx.x;
    if (tid == 0) carry_s = 0;
    __syncthreads();
    for (int base = 0; base < N_NODES; base += 1024) {
        int i = base + tid;
        int v = (i < N_NODES) ? deg[i] : 0;
        buf[tid] = v;
        __syncthreads();
        for (int off = 1; off < 1024; off <<= 1) {
            int t = (tid >= off) ? buf[tid - off] : 0;
            __syncthreads();
            buf[tid] += t;
            __syncthreads();
        }
        int excl = buf[tid] - v;
        int carry = carry_s;
        if (i < N_NODES) { row_ptr[i] = carry + excl; cursor[i] = carry + excl; }
        __syncthreads();
        if (tid == 0) carry_s = carry + buf[1023];
        __syncthreads();
    }
    if (tid == 0) row_ptr[N_NODES] = carry_s;
}

__global__ void fill_kernel(const int* __restrict__ ei, int* __restrict__ cursor,
                            int* __restrict__ col_src) {
    int e = blockIdx.x * blockDim.x + threadIdx.x;
    if (e >= N_EDGES) return;
    int d = ei[N_EDGES + e];
    int pos = atomicAdd(&cursor[d], 1);
    col_src[pos] = ei[e];
}

// ---------------------------------------------------------------------------
// pad x [N,128] -> h [N,256]
// ---------------------------------------------------------------------------
__global__ __launch_bounds__(256) void pad_kernel(const float* __restrict__ x,
                                                  float* __restrict__ H) {
    int t = blockIdx.x * 256 + threadIdx.x;
    int node = t >> 6, q = t & 63;
    if (node >= N_NODES) return;
    float4 v = make_float4(0.f, 0.f, 0.f, 0.f);
    if (q < 32) v = *(const float4*)(x + (size_t)node * IN_DIM + q * 4);
    *(float4*)(H + (size_t)node * C + q * 4) = v;
}

// ---------------------------------------------------------------------------
// s[d] = sum_{e: dst==d} h[src_e]   (one wave per destination node)
// ---------------------------------------------------------------------------
__global__ __launch_bounds__(256) void gather_kernel(const float* __restrict__ H,
                                                     const int* __restrict__ row_ptr,
                                                     const int* __restrict__ col_src,
                                                     float* __restrict__ S) {
    int wave = threadIdx.x >> 6, lane = threadIdx.x & 63;
    int node = blockIdx.x * 4 + wave;
    if (node >= N_NODES) return;
    int beg = row_ptr[node], end = row_ptr[node + 1];
    float4 acc = make_float4(0.f, 0.f, 0.f, 0.f);
    for (int p = beg; p < end; ++p) {
        int s = col_src[p];
        float4 v = *(const float4*)(H + (size_t)s * C + lane * 4);
        acc.x += v.x; acc.y += v.y; acc.z += v.z; acc.w += v.w;
    }
    *(float4*)(S + (size_t)node * C + lane * 4) = acc;
}

// ---------------------------------------------------------------------------
// agg = S @ W   (64x64 tile, 4x4 per thread, fp32)
// ---------------------------------------------------------------------------
__global__ __launch_bounds__(256) void gemm_agg(const float* __restrict__ S,
                                                const float* __restrict__ W,
                                                float* __restrict__ agg) {
    __shared__ float As[16][64];
    __shared__ float Bs[16][64];
    const int tid = threadIdx.x;
    const int n0 = blockIdx.x * 64, j0 = blockIdx.y * 64;
    const int ty = tid >> 4, tx = tid & 15;
    const int lrow = tid >> 2, lk4 = (tid & 3) * 4;
    float acc[4][4] = {};
    for (int k0 = 0; k0 < C; k0 += 16) {
        float4 a = make_float4(0.f, 0.f, 0.f, 0.f);
        int gr = n0 + lrow;
        if (gr < N_NODES) a = *(const float4*)(S + (size_t)gr * C + k0 + lk4);
        As[lk4 + 0][lrow] = a.x; As[lk4 + 1][lrow] = a.y;
        As[lk4 + 2][lrow] = a.z; As[lk4 + 3][lrow] = a.w;
        float4 b = *(const float4*)(W + (size_t)(k0 + (tid >> 4)) * C + j0 + tx * 4);
        *(float4*)&Bs[tid >> 4][tx * 4] = b;
        __syncthreads();
#pragma unroll
        for (int kk = 0; kk < 16; ++kk) {
            float4 av = *(const float4*)&As[kk][ty * 4];
            float4 bv = *(const float4*)&Bs[kk][tx * 4];
            float af[4] = {av.x, av.y, av.z, av.w};
            float bf[4] = {bv.x, bv.y, bv.z, bv.w};
#pragma unroll
            for (int i = 0; i < 4; i++)
#pragma unroll
                for (int j = 0; j < 4; j++) acc[i][j] += af[i] * bf[j];
        }
        __syncthreads();
    }
#pragma unroll
    for (int i = 0; i < 4; i++) {
        int gr = n0 + ty * 4 + i;
        if (gr < N_NODES)
            *(float4*)(agg + (size_t)gr * C + j0 + tx * 4) =
                make_float4(acc[i][0], acc[i][1], acc[i][2], acc[i][3]);
    }
}

// ---------------------------------------------------------------------------
// Fused GRU: 6 accumulators (i_r,i_z,i_n from agg@w_ih^T; h_r,h_z,h_n from h@w_hh^T)
// then gates + new h, all in one kernel. 64 rows x 64 cols per block.
// ---------------------------------------------------------------------------
__global__ __launch_bounds__(256) void gru_kernel(const float* __restrict__ AGG,
                                                  const float* __restrict__ H,
                                                  const float* __restrict__ w_ih,
                                                  const float* __restrict__ w_hh,
                                                  const float* __restrict__ b_ih,
                                                  const float* __restrict__ b_hh,
                                                  float* __restrict__ Hout) {
    __shared__ float Aa[16][64];
    __shared__ float Ah[16][64];
    __shared__ float Bs[6][16][64];
    const int tid = threadIdx.x;
    const int n0 = blockIdx.x * 64, c0 = blockIdx.y * 64;
    const int ty = tid >> 4, tx = tid & 15;
    const int lrow = tid >> 2, lk4 = (tid & 3) * 4;
    float acc[6][4][4] = {};
    for (int k0 = 0; k0 < C; k0 += 16) {
        int gr = n0 + lrow;
        float4 a = make_float4(0.f, 0.f, 0.f, 0.f);
        float4 ah = make_float4(0.f, 0.f, 0.f, 0.f);
        if (gr < N_NODES) {
            a  = *(const float4*)(AGG + (size_t)gr * C + k0 + lk4);
            ah = *(const float4*)(H   + (size_t)gr * C + k0 + lk4);
        }
        Aa[lk4 + 0][lrow] = a.x;  Aa[lk4 + 1][lrow] = a.y;
        Aa[lk4 + 2][lrow] = a.z;  Aa[lk4 + 3][lrow] = a.w;
        Ah[lk4 + 0][lrow] = ah.x; Ah[lk4 + 1][lrow] = ah.y;
        Ah[lk4 + 2][lrow] = ah.z; Ah[lk4 + 3][lrow] = ah.w;
#pragma unroll
        for (int q = 0; q < 6; q++) {
            const float* Wp = (q < 3) ? w_ih : w_hh;
            int off = (q % 3) * 256;
            float4 b = *(const float4*)(Wp + (size_t)(c0 + lrow + off) * C + k0 + lk4);
            Bs[q][lk4 + 0][lrow] = b.x; Bs[q][lk4 + 1][lrow] = b.y;
            Bs[q][lk4 + 2][lrow] = b.z; Bs[q][lk4 + 3][lrow] = b.w;
        }
        __syncthreads();
#pragma unroll
        for (int kk = 0; kk < 16; ++kk) {
            float4 aa = *(const float4*)&Aa[kk][ty * 4];
            float4 hh = *(const float4*)&Ah[kk][ty * 4];
            float av[2][4] = {{aa.x, aa.y, aa.z, aa.w}, {hh.x, hh.y, hh.z, hh.w}};
#pragma unroll
            for (int q = 0; q < 6; q++) {
                float4 bb = *(const float4*)&Bs[q][kk][tx * 4];
                float bf[4] = {bb.x, bb.y, bb.z, bb.w};
                const float* ap = av[(q < 3) ? 0 : 1];
#pragma unroll
                for (int i = 0; i < 4; i++)
#pragma unroll
                    for (int j = 0; j < 4; j++) acc[q][i][j] += ap[i] * bf[j];
            }
        }
        __syncthreads();
    }
#pragma unroll
    for (int i = 0; i < 4; i++) {
        int gr = n0 + ty * 4 + i;
        if (gr >= N_NODES) continue;
        float4 h4 = *(const float4*)(H + (size_t)gr * C + c0 + tx * 4);
        float hold[4] = {h4.x, h4.y, h4.z, h4.w};
        float res[4];
#pragma unroll
        for (int j = 0; j < 4; j++) {
            int cc = c0 + tx * 4 + j;
            float ir = acc[0][i][j] + b_ih[cc];
            float iz = acc[1][i][j] + b_ih[cc + 256];
            float in_ = acc[2][i][j] + b_ih[cc + 512];
            float hr = acc[3][i][j] + b_hh[cc];
            float hz = acc[4][i][j] + b_hh[cc + 256];
            float hn = acc[5][i][j] + b_hh[cc + 512];
            float r = 1.f / (1.f + expf(-(ir + hr)));
            float z = 1.f / (1.f + expf(-(iz + hz)));
            float nn = tanhf(in_ + r * hn);
            res[j] = (1.f - z) * nn + z * hold[j];
        }
        *(float4*)(Hout + (size_t)gr * C + c0 + tx * 4) =
            make_float4(res[0], res[1], res[2], res[3]);
    }
}

// ---------------------------------------------------------------------------
// mean pool (atomic accumulate) + classifier
// ---------------------------------------------------------------------------
__global__ __launch_bounds__(256) void pool_kernel(const float* __restrict__ H,
                                                   const int* __restrict__ batch,
                                                   float* __restrict__ gsum,
                                                   float* __restrict__ counts) {
    int wave = threadIdx.x >> 6, lane = threadIdx.x & 63;
    int node = blockIdx.x * 4 + wave;
    if (node >= N_NODES) return;
    int b = batch[node];
    float4 v = *(const float4*)(H + (size_t)node * C + lane * 4);
    atomicAdd(&gsum[b * C + lane * 4 + 0], v.x);
    atomicAdd(&gsum[b * C + lane * 4 + 1], v.y);
    atomicAdd(&gsum[b * C + lane * 4 + 2], v.z);
    atomicAdd(&gsum[b * C + lane * 4 + 3], v.w);
    if (lane == 0) atomicAdd(&counts[b], 1.0f);
}

__global__ __launch_bounds__(128) void cls_kernel(const float* __restrict__ gsum,
                                                  const float* __restrict__ counts,
                                                  const float* __restrict__ W1,
                                                  const float* __restrict__ b1,
                                                  const float* __restrict__ W2,
                                                  const float* __restrict__ b2,
                                                  float* __restrict__ out) {
    int b = blockIdx.x, j = threadIdx.x;
    float inv = 1.0f / fmaxf(counts[b], 1.0f);
    float acc = b1[j];
    for (int k = 0; k < C; k += 4) {
        float4 g = *(const float4*)(gsum + (size_t)b * C + k);
        float4 w = *(const float4*)(W1 + (size_t)j * C + k);
        acc += (g.x * w.x + g.y * w.y + g.z * w.z + g.w * w.w) * inv;
    }
    float hc = fmaxf(acc, 0.f);
    float v = W2[j] * hc;
    __shared__ float red[128];
    red[j] = v;
    __syncthreads();
    for (int s = 64; s > 0; s >>= 1) {
        if (j < s) red[j] += red[j + s];
        __syncthreads();
    }
    if (j == 0) out[b] = 1.f / (1.f + expf(-(red[0] + b2[0])));
}

// ---------------------------------------------------------------------------
extern "C" void kernel_launch(void* const* d_in, const int* in_sizes, int n_in,
                              void* d_out, int out_size, void* d_ws, size_t ws_size,
                              hipStream_t stream) {
    const float* x      = (const float*)d_in[0];
    const int*   ei     = (const int*)d_in[1];
    const int*   batch  = (const int*)d_in[2];
    const float* weight = (const float*)d_in[3];
    const float* w_ih   = (const float*)d_in[4];
    const float* w_hh   = (const float*)d_in[5];
    const float* b_ih   = (const float*)d_in[6];
    const float* b_hh   = (const float*)d_in[7];
    const float* W1     = (const float*)d_in[8];
    const float* b1     = (const float*)d_in[9];
    const float* W2     = (const float*)d_in[10];
    const float* b2     = (const float*)d_in[11];
    float* out = (float*)d_out;

    char* ws = (char*)d_ws;
    size_t o = 0;
    auto alloc = [&](size_t bytes) {
        void* p = ws + o;
        o = (o + bytes + 255) & ~(size_t)255;
        return p;
    };
    float* hA   = (float*)alloc((size_t)N_NODES * C * 4);
    float* hB   = (float*)alloc((size_t)N_NODES * C * 4);
    float* sbuf = (float*)alloc((size_t)N_NODES * C * 4);
    float* agg  = (float*)alloc((size_t)N_NODES * C * 4);
    float* gsum = (float*)alloc((size_t)N_GRAPHS * C * 4);
    float* cnts = (float*)alloc((size_t)N_GRAPHS * 4);
    int* deg     = (int*)alloc((size_t)N_NODES * 4);
    int* row_ptr = (int*)alloc((size_t)(N_NODES + 1) * 4);
    int* cursor  = (int*)alloc((size_t)N_NODES * 4);
    int* col_src = (int*)alloc((size_t)N_EDGES * 4);

    // CSR build (every call — harness re-poisons ws)
    hipMemsetAsync(deg, 0, (size_t)N_NODES * 4, stream);
    count_kernel<<<(N_EDGES + 255) / 256, 256, 0, stream>>>(ei, deg);
    scan_kernel<<<1, 1024, 0, stream>>>(deg, row_ptr, cursor);
    fill_kernel<<<(N_EDGES + 255) / 256, 256, 0, stream>>>(ei, cursor, col_src);

    // h0 = pad(x)
    pad_kernel<<<(N_NODES * 64) / 256, 256, 0, stream>>>(x, hA);

    const int gx = (N_NODES + 63) / 64;  // 782
    float* hcur = hA;
    float* hnxt = hB;
    for (int l = 0; l < LAYERS; ++l) {
        gather_kernel<<<(N_NODES + 3) / 4, 256, 0, stream>>>(hcur, row_ptr, col_src, sbuf);
        gemm_agg<<<dim3(gx, C / 64), 256, 0, stream>>>(sbuf, weight + (size_t)l * C * C, agg);
        gru_kernel<<<dim3(gx, C / 64), 256, 0, stream>>>(agg, hcur, w_ih, w_hh, b_ih, b_hh, hnxt);
        float* t = hcur; hcur = hnxt; hnxt = t;
    }

    // pooling + classifier
    hipMemsetAsync(gsum, 0, (size_t)N_GRAPHS * C * 4, stream);
    hipMemsetAsync(cnts, 0, (size_t)N_GRAPHS * 4, stream);
    pool_kernel<<<(N_NODES + 3) / 4, 256, 0, stream>>>(hcur, batch, gsum, cnts);
    cls_kernel<<<N_GRAPHS, 128, 0, stream>>>(gsum, cnts, W1, b1, W2, b2, out);
}

// Round 4
// 2075.065 us; speedup vs baseline: 3.3161x; 3.3161x over previous
//
#include <hip/hip_runtime.h>
#include <hip/hip_bf16.h>
#include <math.h>

#define N_NODES 50000
#define NPAD    50048            // 782 * 64
#define N_EDGES 300000
#define IN_DIM  128
#define C       256
#define LAYERS  6
#define N_GRAPHS 256

typedef __attribute__((ext_vector_type(8))) short v8s;
typedef __attribute__((ext_vector_type(4))) float v4f;

__device__ __forceinline__ unsigned short f2b(float f) {   // fp32 -> bf16 RNE
    unsigned int u = __float_as_uint(f);
    unsigned int r = (u + 0x7FFFu + ((u >> 16) & 1u)) >> 16;
    return (unsigned short)r;
}
__device__ __forceinline__ float b2f(unsigned short b) {
    return __uint_as_float(((unsigned int)b) << 16);
}

// ---------------------------------------------------------------------------
// CSR build
// ---------------------------------------------------------------------------
__global__ void count_kernel(const int* __restrict__ ei, int* __restrict__ deg) {
    int e = blockIdx.x * blockDim.x + threadIdx.x;
    if (e < N_EDGES) atomicAdd(&deg[ei[N_EDGES + e]], 1);
}

__global__ void scan_kernel(const int* __restrict__ deg, int* __restrict__ row_ptr,
                            int* __restrict__ cursor) {
    __shared__ int buf[1024];
    __shared__ int carry_s;
    int tid = threadIdx.x;
    if (tid == 0) carry_s = 0;
    __syncthreads();
    for (int base = 0; base < N_NODES; base += 1024) {
        int i = base + tid;
        int v = (i < N_NODES) ? deg[i] : 0;
        buf[tid] = v;
        __syncthreads();
        for (int off = 1; off < 1024; off <<= 1) {
            int t = (tid >= off) ? buf[tid - off] : 0;
            __syncthreads();
            buf[tid] += t;
            __syncthreads();
        }
        int excl = buf[tid] - v;
        int carry = carry_s;
        if (i < N_NODES) { row_ptr[i] = carry + excl; cursor[i] = carry + excl; }
        __syncthreads();
        if (tid == 0) carry_s = carry + buf[1023];
        __syncthreads();
    }
    if (tid == 0) row_ptr[N_NODES] = carry_s;
}

__global__ void fill_kernel(const int* __restrict__ ei, int* __restrict__ cursor,
                            int* __restrict__ col_src) {
    int e = blockIdx.x * blockDim.x + threadIdx.x;
    if (e >= N_EDGES) return;
    int d = ei[N_EDGES + e];
    int pos = atomicAdd(&cursor[d], 1);
    col_src[pos] = ei[e];
}

// ---------------------------------------------------------------------------
// weight prep: fp32 -> bf16 (and transpose for `weight`)
// ---------------------------------------------------------------------------
__global__ __launch_bounds__(256) void conv_gates(const float* __restrict__ wih,
                                                  const float* __restrict__ whh,
                                                  unsigned short* __restrict__ wihb,
                                                  unsigned short* __restrict__ whhb) {
    int t = blockIdx.x * 256 + threadIdx.x;
    if (t < 3 * C * C) { wihb[t] = f2b(wih[t]); whhb[t] = f2b(whh[t]); }
}

__global__ __launch_bounds__(256) void transpose_weight(const float* __restrict__ w,
                                                        unsigned short* __restrict__ wt) {
    int t = blockIdx.x * 256 + threadIdx.x;   // 6*256*256
    if (t >= LAYERS * C * C) return;
    int l = t >> 16, rem = t & 65535;
    int k = rem >> 8, j = rem & 255;
    wt[l * 65536 + j * 256 + k] = f2b(w[l * 65536 + k * 256 + j]);
}

// ---------------------------------------------------------------------------
// pad x [N,128] -> Hb bf16 [NPAD,256]  (pad rows zeroed)
// ---------------------------------------------------------------------------
__global__ __launch_bounds__(256) void pad_kernel(const float* __restrict__ x,
                                                  unsigned short* __restrict__ Hb) {
    int t = blockIdx.x * 256 + threadIdx.x;   // NPAD*32 threads, 8 cols each
    int node = t >> 5, q = t & 31;
    if (node >= NPAD) return;
    v8s out = {0, 0, 0, 0, 0, 0, 0, 0};
    if (node < N_NODES && q < 16) {
        const float* xp = x + (size_t)node * IN_DIM + q * 8;
        float4 a = *(const float4*)xp;
        float4 b = *(const float4*)(xp + 4);
        out[0] = (short)f2b(a.x); out[1] = (short)f2b(a.y);
        out[2] = (short)f2b(a.z); out[3] = (short)f2b(a.w);
        out[4] = (short)f2b(b.x); out[5] = (short)f2b(b.y);
        out[6] = (short)f2b(b.z); out[7] = (short)f2b(b.w);
    }
    *(v8s*)(Hb + (size_t)node * C + q * 8) = out;
}

// ---------------------------------------------------------------------------
// S[d] = sum_{e: dst==d} h[src_e]   bf16 in / fp32 acc / bf16 out
// ---------------------------------------------------------------------------
__global__ __launch_bounds__(256) void gather_bf16(const unsigned short* __restrict__ Hb,
                                                   const int* __restrict__ row_ptr,
                                                   const int* __restrict__ col_src,
                                                   unsigned short* __restrict__ Sb) {
    int wave = threadIdx.x >> 6, lane = threadIdx.x & 63;
    int node = blockIdx.x * 4 + wave;
    if (node >= N_NODES) return;
    int beg = row_ptr[node], end = row_ptr[node + 1];
    float a0 = 0.f, a1 = 0.f, a2 = 0.f, a3 = 0.f;
    for (int p = beg; p < end; ++p) {
        int s = col_src[p];
        uint2 raw = *(const uint2*)(Hb + (size_t)s * C + lane * 4);
        a0 += __uint_as_float((raw.x & 0xFFFFu) << 16);
        a1 += __uint_as_float(raw.x & 0xFFFF0000u);
        a2 += __uint_as_float((raw.y & 0xFFFFu) << 16);
        a3 += __uint_as_float(raw.y & 0xFFFF0000u);
    }
    uint2 out;
    out.x = (unsigned int)f2b(a0) | ((unsigned int)f2b(a1) << 16);
    out.y = (unsigned int)f2b(a2) | ((unsigned int)f2b(a3) << 16);
    *(uint2*)(Sb + (size_t)node * C + lane * 4) = out;
}

// ---------------------------------------------------------------------------
// Mb = Sb @ Wt^T  (Wt pre-transposed: Wt[j][k] = weight[k][j]) — pure MFMA,
// no LDS. 64x64 tile, 4 waves (2x2), each wave 32x32.
// ---------------------------------------------------------------------------
__global__ __launch_bounds__(256) void gemm_agg_mfma(const unsigned short* __restrict__ Sb,
                                                     const unsigned short* __restrict__ Wt,
                                                     unsigned short* __restrict__ Mb) {
    const int tid = threadIdx.x;
    const int lane = tid & 63, wid = tid >> 6;
    const int wr = wid >> 1, wc = wid & 1;
    const int n0 = blockIdx.x * 64 + wr * 32;
    const int c0 = blockIdx.y * 64 + wc * 32;
    const int lr = lane & 15;
    const int kg = (lane >> 4) * 8;

    v4f acc[2][2] = {};
    for (int k0 = 0; k0 < C; k0 += 32) {
        v8s a[2], b[2];
#pragma unroll
        for (int f = 0; f < 2; f++) {
            a[f] = *(const v8s*)(Sb + (size_t)(n0 + f * 16 + lr) * C + k0 + kg);
            b[f] = *(const v8s*)(Wt + (size_t)(c0 + f * 16 + lr) * C + k0 + kg);
        }
#pragma unroll
        for (int fi = 0; fi < 2; fi++)
#pragma unroll
            for (int fj = 0; fj < 2; fj++)
                acc[fi][fj] = __builtin_amdgcn_mfma_f32_16x16x32_bf16(a[fi], b[fj],
                                                                      acc[fi][fj], 0, 0, 0);
    }
    const int rbase = (lane >> 4) * 4;
#pragma unroll
    for (int fi = 0; fi < 2; fi++)
#pragma unroll
        for (int fj = 0; fj < 2; fj++) {
            int col = c0 + fj * 16 + lr;
#pragma unroll
            for (int r = 0; r < 4; r++) {
                int row = n0 + fi * 16 + rbase + r;
                Mb[(size_t)row * C + col] = f2b(acc[fi][fj][r]);
            }
        }
}

// ---------------------------------------------------------------------------
// Fused GRU via MFMA: 6 gate GEMMs share two A-streams (Mb=agg, Hb=h).
// All operands K-contiguous -> direct 16B global loads, no LDS, no barriers.
// ---------------------------------------------------------------------------
__global__ __launch_bounds__(256) void gru_mfma(const unsigned short* __restrict__ Mb,
                                                const unsigned short* __restrict__ Hb,
                                                const unsigned short* __restrict__ wihb,
                                                const unsigned short* __restrict__ whhb,
                                                const float* __restrict__ b_ih,
                                                const float* __restrict__ b_hh,
                                                unsigned short* __restrict__ Hout) {
    const int tid = threadIdx.x;
    const int lane = tid & 63, wid = tid >> 6;
    const int wr = wid >> 1, wc = wid & 1;
    const int n0 = blockIdx.x * 64 + wr * 32;
    const int c0 = blockIdx.y * 64 + wc * 32;
    const int lr = lane & 15;
    const int kg = (lane >> 4) * 8;

    v4f acc[6][2][2] = {};
    for (int k0 = 0; k0 < C; k0 += 32) {
        v8s a[2][2];   // [stream: 0=agg, 1=h][fi]
#pragma unroll
        for (int fi = 0; fi < 2; fi++) {
            size_t ro = (size_t)(n0 + fi * 16 + lr) * C + k0 + kg;
            a[0][fi] = *(const v8s*)(Mb + ro);
            a[1][fi] = *(const v8s*)(Hb + ro);
        }
#pragma unroll
        for (int q = 0; q < 6; q++) {
            const unsigned short* W = (q < 3) ? wihb : whhb;
            int goff = (q % 3) * C;
#pragma unroll
            for (int fj = 0; fj < 2; fj++) {
                v8s b = *(const v8s*)(W + (size_t)(goff + c0 + fj * 16 + lr) * C + k0 + kg);
#pragma unroll
                for (int fi = 0; fi < 2; fi++)
                    acc[q][fi][fj] = __builtin_amdgcn_mfma_f32_16x16x32_bf16(
                        a[q / 3][fi], b, acc[q][fi][fj], 0, 0, 0);
            }
        }
    }
    // epilogue: gates in fp32
    const int rbase = (lane >> 4) * 4;
#pragma unroll
    for (int fj = 0; fj < 2; fj++) {
        int col = c0 + fj * 16 + lr;
        float bir = b_ih[col], biz = b_ih[col + 256], bin = b_ih[col + 512];
        float bhr = b_hh[col], bhz = b_hh[col + 256], bhn = b_hh[col + 512];
#pragma unroll
        for (int fi = 0; fi < 2; fi++)
#pragma unroll
            for (int r = 0; r < 4; r++) {
                int row = n0 + fi * 16 + rbase + r;
                float hold = b2f(Hb[(size_t)row * C + col]);
                float ir = acc[0][fi][fj][r] + bir;
                float iz = acc[1][fi][fj][r] + biz;
                float in_ = acc[2][fi][fj][r] + bin;
                float hr = acc[3][fi][fj][r] + bhr;
                float hz = acc[4][fi][fj][r] + bhz;
                float hn = acc[5][fi][fj][r] + bhn;
                float rg = 1.f / (1.f + __expf(-(ir + hr)));
                float z  = 1.f / (1.f + __expf(-(iz + hz)));
                float nn = tanhf(in_ + rg * hn);
                float out = (1.f - z) * nn + z * hold;
                Hout[(size_t)row * C + col] = f2b(out);
            }
    }
}

// ---------------------------------------------------------------------------
// mean pool: one block per graph (batch is sorted -> binary search bounds)
// ---------------------------------------------------------------------------
__global__ __launch_bounds__(256) void pool2(const unsigned short* __restrict__ Hb,
                                             const int* __restrict__ batch,
                                             float* __restrict__ g) {
    int b = blockIdx.x, j = threadIdx.x;
    __shared__ int bound[2];
    if (j < 2) {
        int target = b + j;
        int lo = 0, hi = N_NODES;
        while (lo < hi) {
            int mid = (lo + hi) >> 1;
            if (batch[mid] < target) lo = mid + 1; else hi = mid;
        }
        bound[j] = lo;
    }
    __syncthreads();
    int slo = bound[0], shi = bound[1];
    float a0 = 0.f, a1 = 0.f, a2 = 0.f, a3 = 0.f;
    int row = slo;
    for (; row + 3 < shi; row += 4) {
        a0 += b2f(Hb[(size_t)(row + 0) * C + j]);
        a1 += b2f(Hb[(size_t)(row + 1) * C + j]);
        a2 += b2f(Hb[(size_t)(row + 2) * C + j]);
        a3 += b2f(Hb[(size_t)(row + 3) * C + j]);
    }
    for (; row < shi; ++row) a0 += b2f(Hb[(size_t)row * C + j]);
    float acc = (a0 + a1) + (a2 + a3);
    float cnt = (float)(shi - slo);
    g[b * C + j] = acc / fmaxf(cnt, 1.f);
}

__global__ __launch_bounds__(128) void cls_kernel(const float* __restrict__ g,
                                                  const float* __restrict__ W1,
                                                  const float* __restrict__ b1,
                                                  const float* __restrict__ W2,
                                                  const float* __restrict__ b2,
                                                  float* __restrict__ out) {
    int b = blockIdx.x, j = threadIdx.x;
    float acc = b1[j];
    for (int k = 0; k < C; k += 4) {
        float4 gv = *(const float4*)(g + (size_t)b * C + k);
        float4 wv = *(const float4*)(W1 + (size_t)j * C + k);
        acc += gv.x * wv.x + gv.y * wv.y + gv.z * wv.z + gv.w * wv.w;
    }
    float hc = fmaxf(acc, 0.f);
    float v = W2[j] * hc;
    __shared__ float red[128];
    red[j] = v;
    __syncthreads();
    for (int s = 64; s > 0; s >>= 1) {
        if (j < s) red[j] += red[j + s];
        __syncthreads();
    }
    if (j == 0) out[b] = 1.f / (1.f + __expf(-(red[0] + b2[0])));
}

// ---------------------------------------------------------------------------
extern "C" void kernel_launch(void* const* d_in, const int* in_sizes, int n_in,
                              void* d_out, int out_size, void* d_ws, size_t ws_size,
                              hipStream_t stream) {
    const float* x      = (const float*)d_in[0];
    const int*   ei     = (const int*)d_in[1];
    const int*   batch  = (const int*)d_in[2];
    const float* weight = (const float*)d_in[3];
    const float* w_ih   = (const float*)d_in[4];
    const float* w_hh   = (const float*)d_in[5];
    const float* b_ih   = (const float*)d_in[6];
    const float* b_hh   = (const float*)d_in[7];
    const float* W1     = (const float*)d_in[8];
    const float* b1     = (const float*)d_in[9];
    const float* W2     = (const float*)d_in[10];
    const float* b2     = (const float*)d_in[11];
    float* out = (float*)d_out;

    char* ws = (char*)d_ws;
    size_t o = 0;
    auto alloc = [&](size_t bytes) {
        void* p = ws + o;
        o = (o + bytes + 255) & ~(size_t)255;
        return p;
    };
    unsigned short* HbA = (unsigned short*)alloc((size_t)NPAD * C * 2);
    unsigned short* HbB = (unsigned short*)alloc((size_t)NPAD * C * 2);
    unsigned short* Sb  = (unsigned short*)alloc((size_t)NPAD * C * 2);
    unsigned short* Mb  = (unsigned short*)alloc((size_t)NPAD * C * 2);
    unsigned short* wihb = (unsigned short*)alloc((size_t)3 * C * C * 2);
    unsigned short* whhb = (unsigned short*)alloc((size_t)3 * C * C * 2);
    unsigned short* Wtb  = (unsigned short*)alloc((size_t)LAYERS * C * C * 2);
    float* g = (float*)alloc((size_t)N_GRAPHS * C * 4);
    int* deg     = (int*)alloc((size_t)N_NODES * 4);
    int* row_ptr = (int*)alloc((size_t)(N_NODES + 1) * 4);
    int* cursor  = (int*)alloc((size_t)N_NODES * 4);
    int* col_src = (int*)alloc((size_t)N_EDGES * 4);

    // weight prep + CSR build
    conv_gates<<<(3 * C * C + 255) / 256, 256, 0, stream>>>(w_ih, w_hh, wihb, whhb);
    transpose_weight<<<(LAYERS * C * C + 255) / 256, 256, 0, stream>>>(weight, Wtb);
    hipMemsetAsync(deg, 0, (size_t)N_NODES * 4, stream);
    count_kernel<<<(N_EDGES + 255) / 256, 256, 0, stream>>>(ei, deg);
    scan_kernel<<<1, 1024, 0, stream>>>(deg, row_ptr, cursor);
    fill_kernel<<<(N_EDGES + 255) / 256, 256, 0, stream>>>(ei, cursor, col_src);

    // h0 = pad(x) -> bf16
    pad_kernel<<<(NPAD * 32) / 256, 256, 0, stream>>>(x, HbA);

    const int gx = NPAD / 64;  // 782
    unsigned short* hcur = HbA;
    unsigned short* hnxt = HbB;
    for (int l = 0; l < LAYERS; ++l) {
        gather_bf16<<<(N_NODES + 3) / 4, 256, 0, stream>>>(hcur, row_ptr, col_src, Sb);
        gemm_agg_mfma<<<dim3(gx, C / 64), 256, 0, stream>>>(Sb, Wtb + (size_t)l * C * C, Mb);
        gru_mfma<<<dim3(gx, C / 64), 256, 0, stream>>>(Mb, hcur, wihb, whhb, b_ih, b_hh, hnxt);
        unsigned short* t = hcur; hcur = hnxt; hnxt = t;
    }

    pool2<<<N_GRAPHS, 256, 0, stream>>>(hcur, batch, g);
    cls_kernel<<<N_GRAPHS, 128, 0, stream>>>(g, W1, b1, W2, b2, out);
}

// Round 5
// 1883.547 us; speedup vs baseline: 3.6533x; 1.1017x over previous
//
#include <hip/hip_runtime.h>
#include <hip/hip_bf16.h>
#include <math.h>

#define N_NODES 50000
#define NPAD    50048            // 782 * 64 = 391 * 128
#define N_EDGES 300000
#define IN_DIM  128
#define C       256
#define LAYERS  6
#define N_GRAPHS 256

typedef __attribute__((ext_vector_type(8))) short v8s;
typedef __attribute__((ext_vector_type(4))) float v4f;

__device__ __forceinline__ unsigned short f2b(float f) {   // fp32 -> bf16 RNE
    unsigned int u = __float_as_uint(f);
    unsigned int r = (u + 0x7FFFu + ((u >> 16) & 1u)) >> 16;
    return (unsigned short)r;
}
__device__ __forceinline__ float b2f(unsigned short b) {
    return __uint_as_float(((unsigned int)b) << 16);
}

// ---------------------------------------------------------------------------
// CSR build
// ---------------------------------------------------------------------------
__global__ void count_kernel(const int* __restrict__ ei, int* __restrict__ deg) {
    int e = blockIdx.x * blockDim.x + threadIdx.x;
    if (e < N_EDGES) atomicAdd(&deg[ei[N_EDGES + e]], 1);
}

__global__ void scan_kernel(const int* __restrict__ deg, int* __restrict__ row_ptr,
                            int* __restrict__ cursor) {
    __shared__ int buf[1024];
    __shared__ int carry_s;
    int tid = threadIdx.x;
    if (tid == 0) carry_s = 0;
    __syncthreads();
    for (int base = 0; base < N_NODES; base += 1024) {
        int i = base + tid;
        int v = (i < N_NODES) ? deg[i] : 0;
        buf[tid] = v;
        __syncthreads();
        for (int off = 1; off < 1024; off <<= 1) {
            int t = (tid >= off) ? buf[tid - off] : 0;
            __syncthreads();
            buf[tid] += t;
            __syncthreads();
        }
        int excl = buf[tid] - v;
        int carry = carry_s;
        if (i < N_NODES) { row_ptr[i] = carry + excl; cursor[i] = carry + excl; }
        __syncthreads();
        if (tid == 0) carry_s = carry + buf[1023];
        __syncthreads();
    }
    if (tid == 0) row_ptr[N_NODES] = carry_s;
}

__global__ void fill_kernel(const int* __restrict__ ei, int* __restrict__ cursor,
                            int* __restrict__ col_src) {
    int e = blockIdx.x * blockDim.x + threadIdx.x;
    if (e >= N_EDGES) return;
    int d = ei[N_EDGES + e];
    int pos = atomicAdd(&cursor[d], 1);
    col_src[pos] = ei[e];
}

// ---------------------------------------------------------------------------
// weight prep:
//  Wf  [512][512]: row j<256 -> r-gate col j, row j>=256 -> z-gate col j-256;
//                  col k<256 -> wih[j][k], col k>=256 -> whh[j][k-256]
//  Wni [256][256]: wih rows 512..767 (i_n);  Wnh: whh rows 512..767 (h_n)
//  Wt  [6][256][256]: weight transposed per layer (Wt[l][j][k] = w[l][k][j])
// ---------------------------------------------------------------------------
__global__ __launch_bounds__(256) void prep_gates(const float* __restrict__ wih,
                                                  const float* __restrict__ whh,
                                                  unsigned short* __restrict__ Wf,
                                                  unsigned short* __restrict__ Wni,
                                                  unsigned short* __restrict__ Wnh) {
    int t = blockIdx.x * 256 + threadIdx.x;
    if (t < 512 * 512) {
        int j = t >> 9, k = t & 511;
        float v = (k < 256) ? wih[j * 256 + k] : whh[j * 256 + (k - 256)];
        Wf[t] = f2b(v);
    }
    if (t < 256 * 256) {
        int j = t >> 8, k = t & 255;
        Wni[t] = f2b(wih[(512 + j) * 256 + k]);
        Wnh[t] = f2b(whh[(512 + j) * 256 + k]);
    }
}

__global__ __launch_bounds__(256) void transpose_weight(const float* __restrict__ w,
                                                        unsigned short* __restrict__ wt) {
    int t = blockIdx.x * 256 + threadIdx.x;   // 6*256*256
    if (t >= LAYERS * C * C) return;
    int l = t >> 16, rem = t & 65535;
    int k = rem >> 8, j = rem & 255;
    wt[l * 65536 + j * 256 + k] = f2b(w[l * 65536 + k * 256 + j]);
}

// ---------------------------------------------------------------------------
// pad x [N,128] -> Hb bf16 [NPAD,256]  (pad rows zeroed)
// ---------------------------------------------------------------------------
__global__ __launch_bounds__(256) void pad_kernel(const float* __restrict__ x,
                                                  unsigned short* __restrict__ Hb) {
    int t = blockIdx.x * 256 + threadIdx.x;   // NPAD*32 threads, 8 cols each
    int node = t >> 5, q = t & 31;
    if (node >= NPAD) return;
    v8s out = {0, 0, 0, 0, 0, 0, 0, 0};
    if (node < N_NODES && q < 16) {
        const float* xp = x + (size_t)node * IN_DIM + q * 8;
        float4 a = *(const float4*)xp;
        float4 b = *(const float4*)(xp + 4);
        out[0] = (short)f2b(a.x); out[1] = (short)f2b(a.y);
        out[2] = (short)f2b(a.z); out[3] = (short)f2b(a.w);
        out[4] = (short)f2b(b.x); out[5] = (short)f2b(b.y);
        out[6] = (short)f2b(b.z); out[7] = (short)f2b(b.w);
    }
    *(v8s*)(Hb + (size_t)node * C + q * 8) = out;
}

// ---------------------------------------------------------------------------
// S[d] = sum_{e: dst==d} h[src_e]   bf16 in / fp32 acc / bf16 out
// ---------------------------------------------------------------------------
__global__ __launch_bounds__(256) void gather_bf16(const unsigned short* __restrict__ Hb,
                                                   const int* __restrict__ row_ptr,
                                                   const int* __restrict__ col_src,
                                                   unsigned short* __restrict__ Sb) {
    int wave = threadIdx.x >> 6, lane = threadIdx.x & 63;
    int node = blockIdx.x * 4 + wave;
    if (node >= N_NODES) return;
    int beg = row_ptr[node], end = row_ptr[node + 1];
    float a0 = 0.f, a1 = 0.f, a2 = 0.f, a3 = 0.f;
    for (int p = beg; p < end; ++p) {
        int s = col_src[p];
        uint2 raw = *(const uint2*)(Hb + (size_t)s * C + lane * 4);
        a0 += __uint_as_float((raw.x & 0xFFFFu) << 16);
        a1 += __uint_as_float(raw.x & 0xFFFF0000u);
        a2 += __uint_as_float((raw.y & 0xFFFFu) << 16);
        a3 += __uint_as_float(raw.y & 0xFFFF0000u);
    }
    uint2 out;
    out.x = (unsigned int)f2b(a0) | ((unsigned int)f2b(a1) << 16);
    out.y = (unsigned int)f2b(a2) | ((unsigned int)f2b(a3) << 16);
    *(uint2*)(Sb + (size_t)node * C + lane * 4) = out;
}

// ---------------------------------------------------------------------------
// Mb = Sb @ Wt^T — 128x64 tile, 4 waves (2x2), each wave 64 rows x 32 cols.
// 8 MFMA / 6 loads per 32-K step; acc = 8 v4f (32 regs) -> high occupancy.
// ---------------------------------------------------------------------------
__global__ __launch_bounds__(256) void gemm_agg_mfma(const unsigned short* __restrict__ Sb,
                                                     const unsigned short* __restrict__ Wt,
                                                     unsigned short* __restrict__ Mb) {
    const int tid = threadIdx.x;
    const int lane = tid & 63, wid = tid >> 6;
    const int wr = wid >> 1, wc = wid & 1;
    const int n0 = blockIdx.x * 128 + wr * 64;
    const int c0 = blockIdx.y * 64 + wc * 32;
    const int lr = lane & 15;
    const int kg = (lane >> 4) * 8;

    v4f acc[4][2] = {};
    const unsigned short* Ap = Sb + (size_t)(n0 + lr) * C + kg;
    const unsigned short* Bp = Wt + (size_t)(c0 + lr) * C + kg;
#pragma unroll
    for (int ks = 0; ks < 8; ++ks) {
        const int k = ks * 32;
        v8s a[4], b[2];
#pragma unroll
        for (int f = 0; f < 4; f++) a[f] = *(const v8s*)(Ap + (size_t)f * 16 * C + k);
#pragma unroll
        for (int g = 0; g < 2; g++) b[g] = *(const v8s*)(Bp + (size_t)g * 16 * C + k);
#pragma unroll
        for (int f = 0; f < 4; f++)
#pragma unroll
            for (int g = 0; g < 2; g++)
                acc[f][g] = __builtin_amdgcn_mfma_f32_16x16x32_bf16(a[f], b[g], acc[f][g], 0, 0, 0);
    }
    const int rbase = (lane >> 4) * 4;
#pragma unroll
    for (int f = 0; f < 4; f++)
#pragma unroll
        for (int g = 0; g < 2; g++) {
            int col = c0 + g * 16 + lr;
#pragma unroll
            for (int r = 0; r < 4; r++) {
                int row = n0 + f * 16 + rbase + r;
                Mb[(size_t)row * C + col] = f2b(acc[f][g][r]);
            }
        }
}

// ---------------------------------------------------------------------------
// Fused GRU via MFMA with r/z gate fusion:
//   rsum = [Mb|Hb] @ Wf_rows[0..255]   (K=512)
//   zsum = [Mb|Hb] @ Wf_rows[256..511] (K=512)
//   i_n  = Mb @ Wni, h_n = Hb @ Wnh    (K=256 each)
// 4 accumulators (64 regs), 12 MFMA / 8 loads per 32-K step, 16 steps.
// ---------------------------------------------------------------------------
__global__ __launch_bounds__(256) void gru_mfma(const unsigned short* __restrict__ Mb,
                                                const unsigned short* __restrict__ Hb,
                                                const unsigned short* __restrict__ Wf,
                                                const unsigned short* __restrict__ Wni,
                                                const unsigned short* __restrict__ Wnh,
                                                const float* __restrict__ b_ih,
                                                const float* __restrict__ b_hh,
                                                unsigned short* __restrict__ Hout) {
    const int tid = threadIdx.x;
    const int lane = tid & 63, wid = tid >> 6;
    const int wr = wid >> 1, wc = wid & 1;
    const int n0 = blockIdx.x * 64 + wr * 32;
    const int c0 = blockIdx.y * 64 + wc * 32;
    const int lr = lane & 15;
    const int kg = (lane >> 4) * 8;

    v4f aR[2][2] = {}, aZ[2][2] = {}, aNi[2][2] = {}, aNh[2][2] = {};

    const unsigned short* Ar0 = Mb + (size_t)(n0 + lr) * C + kg;
    const unsigned short* Ar1 = Mb + (size_t)(n0 + 16 + lr) * C + kg;
    const unsigned short* Hr0 = Hb + (size_t)(n0 + lr) * C + kg;
    const unsigned short* Hr1 = Hb + (size_t)(n0 + 16 + lr) * C + kg;
    const unsigned short* WfR0 = Wf + (size_t)(c0 + lr) * 512 + kg;
    const unsigned short* WfR1 = Wf + (size_t)(c0 + 16 + lr) * 512 + kg;
    const unsigned short* WfZ0 = Wf + (size_t)(256 + c0 + lr) * 512 + kg;
    const unsigned short* WfZ1 = Wf + (size_t)(256 + c0 + 16 + lr) * 512 + kg;
    const unsigned short* Wi0 = Wni + (size_t)(c0 + lr) * C + kg;
    const unsigned short* Wi1 = Wni + (size_t)(c0 + 16 + lr) * C + kg;
    const unsigned short* Wh0 = Wnh + (size_t)(c0 + lr) * C + kg;
    const unsigned short* Wh1 = Wnh + (size_t)(c0 + 16 + lr) * C + kg;

#pragma unroll
    for (int ks = 0; ks < 16; ++ks) {
        const bool lo = (ks < 8);          // compile-time after unroll
        const int k = ks * 32;             // Wf col
        const int kk = (ks & 7) * 32;      // A / Wn col
        v8s a[2], bR[2], bZ[2], bN[2];
        a[0]  = lo ? *(const v8s*)(Ar0 + kk) : *(const v8s*)(Hr0 + kk);
        a[1]  = lo ? *(const v8s*)(Ar1 + kk) : *(const v8s*)(Hr1 + kk);
        bR[0] = *(const v8s*)(WfR0 + k);
        bR[1] = *(const v8s*)(WfR1 + k);
        bZ[0] = *(const v8s*)(WfZ0 + k);
        bZ[1] = *(const v8s*)(WfZ1 + k);
        bN[0] = lo ? *(const v8s*)(Wi0 + kk) : *(const v8s*)(Wh0 + kk);
        bN[1] = lo ? *(const v8s*)(Wi1 + kk) : *(const v8s*)(Wh1 + kk);
#pragma unroll
        for (int fi = 0; fi < 2; fi++)
#pragma unroll
            for (int fj = 0; fj < 2; fj++) {
                aR[fi][fj] = __builtin_amdgcn_mfma_f32_16x16x32_bf16(a[fi], bR[fj], aR[fi][fj], 0, 0, 0);
                aZ[fi][fj] = __builtin_amdgcn_mfma_f32_16x16x32_bf16(a[fi], bZ[fj], aZ[fi][fj], 0, 0, 0);
                if (lo)
                    aNi[fi][fj] = __builtin_amdgcn_mfma_f32_16x16x32_bf16(a[fi], bN[fj], aNi[fi][fj], 0, 0, 0);
                else
                    aNh[fi][fj] = __builtin_amdgcn_mfma_f32_16x16x32_bf16(a[fi], bN[fj], aNh[fi][fj], 0, 0, 0);
            }
    }

    // epilogue: gates in fp32
    const int rbase = (lane >> 4) * 4;
#pragma unroll
    for (int fj = 0; fj < 2; fj++) {
        int col = c0 + fj * 16 + lr;
        float brz_r = b_ih[col] + b_hh[col];
        float brz_z = b_ih[col + 256] + b_hh[col + 256];
        float bi_n = b_ih[col + 512];
        float bh_n = b_hh[col + 512];
#pragma unroll
        for (int fi = 0; fi < 2; fi++)
#pragma unroll
            for (int r = 0; r < 4; r++) {
                int row = n0 + fi * 16 + rbase + r;
                float hold = b2f(Hb[(size_t)row * C + col]);
                float rg = 1.f / (1.f + __expf(-(aR[fi][fj][r] + brz_r)));
                float z  = 1.f / (1.f + __expf(-(aZ[fi][fj][r] + brz_z)));
                float nn = tanhf(aNi[fi][fj][r] + bi_n + rg * (aNh[fi][fj][r] + bh_n));
                float out = (1.f - z) * nn + z * hold;
                Hout[(size_t)row * C + col] = f2b(out);
            }
    }
}

// ---------------------------------------------------------------------------
// mean pool: one block per graph (batch is sorted -> binary search bounds)
// ---------------------------------------------------------------------------
__global__ __launch_bounds__(256) void pool2(const unsigned short* __restrict__ Hb,
                                             const int* __restrict__ batch,
                                             float* __restrict__ g) {
    int b = blockIdx.x, j = threadIdx.x;
    __shared__ int bound[2];
    if (j < 2) {
        int target = b + j;
        int lo = 0, hi = N_NODES;
        while (lo < hi) {
            int mid = (lo + hi) >> 1;
            if (batch[mid] < target) lo = mid + 1; else hi = mid;
        }
        bound[j] = lo;
    }
    __syncthreads();
    int slo = bound[0], shi = bound[1];
    float a0 = 0.f, a1 = 0.f, a2 = 0.f, a3 = 0.f;
    int row = slo;
    for (; row + 3 < shi; row += 4) {
        a0 += b2f(Hb[(size_t)(row + 0) * C + j]);
        a1 += b2f(Hb[(size_t)(row + 1) * C + j]);
        a2 += b2f(Hb[(size_t)(row + 2) * C + j]);
        a3 += b2f(Hb[(size_t)(row + 3) * C + j]);
    }
    for (; row < shi; ++row) a0 += b2f(Hb[(size_t)row * C + j]);
    float acc = (a0 + a1) + (a2 + a3);
    float cnt = (float)(shi - slo);
    g[b * C + j] = acc / fmaxf(cnt, 1.f);
}

__global__ __launch_bounds__(128) void cls_kernel(const float* __restrict__ g,
                                                  const float* __restrict__ W1,
                                                  const float* __restrict__ b1,
                                                  const float* __restrict__ W2,
                                                  const float* __restrict__ b2,
                                                  float* __restrict__ out) {
    int b = blockIdx.x, j = threadIdx.x;
    float acc = b1[j];
    for (int k = 0; k < C; k += 4) {
        float4 gv = *(const float4*)(g + (size_t)b * C + k);
        float4 wv = *(const float4*)(W1 + (size_t)j * C + k);
        acc += gv.x * wv.x + gv.y * wv.y + gv.z * wv.z + gv.w * wv.w;
    }
    float hc = fmaxf(acc, 0.f);
    float v = W2[j] * hc;
    __shared__ float red[128];
    red[j] = v;
    __syncthreads();
    for (int s = 64; s > 0; s >>= 1) {
        if (j < s) red[j] += red[j + s];
        __syncthreads();
    }
    if (j == 0) out[b] = 1.f / (1.f + __expf(-(red[0] + b2[0])));
}

// ---------------------------------------------------------------------------
extern "C" void kernel_launch(void* const* d_in, const int* in_sizes, int n_in,
                              void* d_out, int out_size, void* d_ws, size_t ws_size,
                              hipStream_t stream) {
    const float* x      = (const float*)d_in[0];
    const int*   ei     = (const int*)d_in[1];
    const int*   batch  = (const int*)d_in[2];
    const float* weight = (const float*)d_in[3];
    const float* w_ih   = (const float*)d_in[4];
    const float* w_hh   = (const float*)d_in[5];
    const float* b_ih   = (const float*)d_in[6];
    const float* b_hh   = (const float*)d_in[7];
    const float* W1     = (const float*)d_in[8];
    const float* b1     = (const float*)d_in[9];
    const float* W2     = (const float*)d_in[10];
    const float* b2     = (const float*)d_in[11];
    float* out = (float*)d_out;

    char* ws = (char*)d_ws;
    size_t o = 0;
    auto alloc = [&](size_t bytes) {
        void* p = ws + o;
        o = (o + bytes + 255) & ~(size_t)255;
        return p;
    };
    unsigned short* HbA = (unsigned short*)alloc((size_t)NPAD * C * 2);
    unsigned short* HbB = (unsigned short*)alloc((size_t)NPAD * C * 2);
    unsigned short* Sb  = (unsigned short*)alloc((size_t)NPAD * C * 2);
    unsigned short* Mb  = (unsigned short*)alloc((size_t)NPAD * C * 2);
    unsigned short* Wfb  = (unsigned short*)alloc((size_t)512 * 512 * 2);
    unsigned short* Wnib = (unsigned short*)alloc((size_t)C * C * 2);
    unsigned short* Wnhb = (unsigned short*)alloc((size_t)C * C * 2);
    unsigned short* Wtb  = (unsigned short*)alloc((size_t)LAYERS * C * C * 2);
    float* g = (float*)alloc((size_t)N_GRAPHS * C * 4);
    int* deg     = (int*)alloc((size_t)N_NODES * 4);
    int* row_ptr = (int*)alloc((size_t)(N_NODES + 1) * 4);
    int* cursor  = (int*)alloc((size_t)N_NODES * 4);
    int* col_src = (int*)alloc((size_t)N_EDGES * 4);

    // weight prep + CSR build
    prep_gates<<<(512 * 512) / 256, 256, 0, stream>>>(w_ih, w_hh, Wfb, Wnib, Wnhb);
    transpose_weight<<<(LAYERS * C * C + 255) / 256, 256, 0, stream>>>(weight, Wtb);
    hipMemsetAsync(deg, 0, (size_t)N_NODES * 4, stream);
    count_kernel<<<(N_EDGES + 255) / 256, 256, 0, stream>>>(ei, deg);
    scan_kernel<<<1, 1024, 0, stream>>>(deg, row_ptr, cursor);
    fill_kernel<<<(N_EDGES + 255) / 256, 256, 0, stream>>>(ei, cursor, col_src);

    // h0 = pad(x) -> bf16
    pad_kernel<<<(NPAD * 32) / 256, 256, 0, stream>>>(x, HbA);

    unsigned short* hcur = HbA;
    unsigned short* hnxt = HbB;
    for (int l = 0; l < LAYERS; ++l) {
        gather_bf16<<<(N_NODES + 3) / 4, 256, 0, stream>>>(hcur, row_ptr, col_src, Sb);
        gemm_agg_mfma<<<dim3(NPAD / 128, C / 64), 256, 0, stream>>>(Sb, Wtb + (size_t)l * C * C, Mb);
        gru_mfma<<<dim3(NPAD / 64, C / 64), 256, 0, stream>>>(Mb, hcur, Wfb, Wnib, Wnhb, b_ih, b_hh, hnxt);
        unsigned short* t = hcur; hcur = hnxt; hnxt = t;
    }

    pool2<<<N_GRAPHS, 256, 0, stream>>>(hcur, batch, g);
    cls_kernel<<<N_GRAPHS, 128, 0, stream>>>(g, W1, b1, W2, b2, out);
}

// Round 6
// 1635.334 us; speedup vs baseline: 4.2078x; 1.1518x over previous
//
#include <hip/hip_runtime.h>
#include <hip/hip_bf16.h>
#include <math.h>

#define N_NODES 50000
#define NPAD    50048            // 782 * 64; 3128 gru blocks = 8 XCDs * 391
#define N_EDGES 300000
#define IN_DIM  128
#define C       256
#define LAYERS  6
#define N_GRAPHS 256

typedef __attribute__((ext_vector_type(8))) short v8s;
typedef __attribute__((ext_vector_type(4))) float v4f;

__device__ __forceinline__ unsigned short f2b(float f) {   // fp32 -> bf16 RNE
    unsigned int u = __float_as_uint(f);
    unsigned int r = (u + 0x7FFFu + ((u >> 16) & 1u)) >> 16;
    return (unsigned short)r;
}
__device__ __forceinline__ float b2f(unsigned short b) {
    return __uint_as_float(((unsigned int)b) << 16);
}

// ---------------------------------------------------------------------------
// CSR build
// ---------------------------------------------------------------------------
__global__ void count_kernel(const int* __restrict__ ei, int* __restrict__ deg) {
    int e = blockIdx.x * blockDim.x + threadIdx.x;
    if (e < N_EDGES) atomicAdd(&deg[ei[N_EDGES + e]], 1);
}

__global__ void scan_kernel(const int* __restrict__ deg, int* __restrict__ row_ptr,
                            int* __restrict__ cursor) {
    __shared__ int buf[1024];
    __shared__ int carry_s;
    int tid = threadIdx.x;
    if (tid == 0) carry_s = 0;
    __syncthreads();
    for (int base = 0; base < N_NODES; base += 1024) {
        int i = base + tid;
        int v = (i < N_NODES) ? deg[i] : 0;
        buf[tid] = v;
        __syncthreads();
        for (int off = 1; off < 1024; off <<= 1) {
            int t = (tid >= off) ? buf[tid - off] : 0;
            __syncthreads();
            buf[tid] += t;
            __syncthreads();
        }
        int excl = buf[tid] - v;
        int carry = carry_s;
        if (i < N_NODES) { row_ptr[i] = carry + excl; cursor[i] = carry + excl; }
        __syncthreads();
        if (tid == 0) carry_s = carry + buf[1023];
        __syncthreads();
    }
    if (tid == 0) row_ptr[N_NODES] = carry_s;
}

__global__ void fill_kernel(const int* __restrict__ ei, int* __restrict__ cursor,
                            int* __restrict__ col_src) {
    int e = blockIdx.x * blockDim.x + threadIdx.x;
    if (e >= N_EDGES) return;
    int d = ei[N_EDGES + e];
    int pos = atomicAdd(&cursor[d], 1);
    col_src[pos] = ei[e];
}

// ---------------------------------------------------------------------------
// weight prep.
//  WH [768][256] = bf16(w_hh)                       (layer-independent)
//  WS [6][768][256]: WS_l[c'][k] = sum_t wih[c'][t] * w_l[k][t]   (fp32 math)
//    (folds the per-layer agg GEMM m = S @ w_l into the gate weights:
//     i_g = (S @ w_l) @ Wih_g^T = S @ (w_l @ Wih_g^T))
// ---------------------------------------------------------------------------
__global__ __launch_bounds__(256) void conv_whh(const float* __restrict__ whh,
                                                unsigned short* __restrict__ WH) {
    int t = blockIdx.x * 256 + threadIdx.x;
    if (t < 768 * 256) WH[t] = f2b(whh[t]);
}

__global__ __launch_bounds__(256) void fuse_ws(const float* __restrict__ wih,
                                               const float* __restrict__ w,
                                               unsigned short* __restrict__ WS) {
    __shared__ float As[16][64];
    __shared__ float Bs[16][64];
    const int j0 = blockIdx.x * 64;          // 12 tiles over 768 gate-rows
    const int k0 = blockIdx.y * 64;          // 4 tiles over 256 k-cols
    const int l  = blockIdx.z;               // 6 layers
    const float* wl = w + (size_t)l * C * C;
    const int tid = threadIdx.x;
    const int ty = tid >> 4, tx = tid & 15;
    const int lrow = tid >> 2, lt4 = (tid & 3) * 4;
    float acc[4][4] = {};
    for (int t0 = 0; t0 < C; t0 += 16) {
        float4 a = *(const float4*)(wih + (size_t)(j0 + lrow) * C + t0 + lt4);
        As[lt4 + 0][lrow] = a.x; As[lt4 + 1][lrow] = a.y;
        As[lt4 + 2][lrow] = a.z; As[lt4 + 3][lrow] = a.w;
        float4 b = *(const float4*)(wl + (size_t)(k0 + lrow) * C + t0 + lt4);
        Bs[lt4 + 0][lrow] = b.x; Bs[lt4 + 1][lrow] = b.y;
        Bs[lt4 + 2][lrow] = b.z; Bs[lt4 + 3][lrow] = b.w;
        __syncthreads();
#pragma unroll
        for (int kk = 0; kk < 16; ++kk) {
            float af[4], bf[4];
#pragma unroll
            for (int i = 0; i < 4; i++) { af[i] = As[kk][ty * 4 + i]; bf[i] = Bs[kk][tx * 4 + i]; }
#pragma unroll
            for (int i = 0; i < 4; i++)
#pragma unroll
                for (int j = 0; j < 4; j++) acc[i][j] += af[i] * bf[j];
        }
        __syncthreads();
    }
    unsigned short* outp = WS + (size_t)l * 768 * C;
#pragma unroll
    for (int i = 0; i < 4; i++)
#pragma unroll
        for (int j = 0; j < 4; j++)
            outp[(size_t)(j0 + ty * 4 + i) * C + k0 + tx * 4 + j] = f2b(acc[i][j]);
}

// ---------------------------------------------------------------------------
// pad x [N,128] -> Hb bf16 [NPAD,256]  (pad rows zeroed)
// ---------------------------------------------------------------------------
__global__ __launch_bounds__(256) void pad_kernel(const float* __restrict__ x,
                                                  unsigned short* __restrict__ Hb) {
    int t = blockIdx.x * 256 + threadIdx.x;   // NPAD*32 threads, 8 cols each
    int node = t >> 5, q = t & 31;
    if (node >= NPAD) return;
    v8s out = {0, 0, 0, 0, 0, 0, 0, 0};
    if (node < N_NODES && q < 16) {
        const float* xp = x + (size_t)node * IN_DIM + q * 8;
        float4 a = *(const float4*)xp;
        float4 b = *(const float4*)(xp + 4);
        out[0] = (short)f2b(a.x); out[1] = (short)f2b(a.y);
        out[2] = (short)f2b(a.z); out[3] = (short)f2b(a.w);
        out[4] = (short)f2b(b.x); out[5] = (short)f2b(b.y);
        out[6] = (short)f2b(b.z); out[7] = (short)f2b(b.w);
    }
    *(v8s*)(Hb + (size_t)node * C + q * 8) = out;
}

// ---------------------------------------------------------------------------
// S[d] = sum_{e: dst==d} h[src_e]   bf16 in / fp32 acc / bf16 out
// ---------------------------------------------------------------------------
__global__ __launch_bounds__(256) void gather_bf16(const unsigned short* __restrict__ Hb,
                                                   const int* __restrict__ row_ptr,
                                                   const int* __restrict__ col_src,
                                                   unsigned short* __restrict__ Sb) {
    int wave = threadIdx.x >> 6, lane = threadIdx.x & 63;
    int node = blockIdx.x * 4 + wave;
    if (node >= N_NODES) return;
    int beg = row_ptr[node], end = row_ptr[node + 1];
    float a0 = 0.f, a1 = 0.f, a2 = 0.f, a3 = 0.f;
    for (int p = beg; p < end; ++p) {
        int s = col_src[p];
        uint2 raw = *(const uint2*)(Hb + (size_t)s * C + lane * 4);
        a0 += __uint_as_float((raw.x & 0xFFFFu) << 16);
        a1 += __uint_as_float(raw.x & 0xFFFF0000u);
        a2 += __uint_as_float((raw.y & 0xFFFFu) << 16);
        a3 += __uint_as_float(raw.y & 0xFFFF0000u);
    }
    uint2 out;
    out.x = (unsigned int)f2b(a0) | ((unsigned int)f2b(a1) << 16);
    out.y = (unsigned int)f2b(a2) | ((unsigned int)f2b(a3) << 16);
    *(uint2*)(Sb + (size_t)node * C + lane * 4) = out;
}

// ---------------------------------------------------------------------------
// Fused GRU via MFMA, agg folded into per-layer WS:
//   r = sigma(S@WS_r + H@WH_r + br),  z likewise
//   n = tanh(S@WS_n + bin + r * (H@WH_n + bhn))
// 4 accumulators, 8 loads / 12 MFMA per 32-K step, 16 steps (K=512 virtual).
// XCD swizzle: 4 col-blocks of each row-chunk run consecutively on one XCD
// so the Sb/Hb row reads hit that XCD's L2.
// ---------------------------------------------------------------------------
__global__ __launch_bounds__(256) void gru_fused(const unsigned short* __restrict__ Sb,
                                                 const unsigned short* __restrict__ Hb,
                                                 const unsigned short* __restrict__ WS,
                                                 const unsigned short* __restrict__ WH,
                                                 const float* __restrict__ b_ih,
                                                 const float* __restrict__ b_hh,
                                                 unsigned short* __restrict__ Hout) {
    const int tid = threadIdx.x;
    const int lane = tid & 63, wid = tid >> 6;
    const int wr = wid >> 1, wc = wid & 1;
    const int p = blockIdx.x;                  // 3128 = 8 * 391
    const int L = (p & 7) * 391 + (p >> 3);    // bijective XCD-chunk remap
    const int n0 = (L >> 2) * 64 + wr * 32;
    const int c0 = (L & 3) * 64 + wc * 32;
    const int lr = lane & 15;
    const int kg = (lane >> 4) * 8;

    const int offA0 = (n0 + lr) * C + kg;
    const int offA1 = (n0 + 16 + lr) * C + kg;
    const int oR0 = (c0 + lr) * C + kg,       oR1 = (c0 + 16 + lr) * C + kg;
    const int oZ0 = oR0 + 256 * C,            oZ1 = oR1 + 256 * C;
    const int oN0 = oR0 + 512 * C,            oN1 = oR1 + 512 * C;

    v4f aR[2][2] = {}, aZ[2][2] = {}, aNi[2][2] = {}, aNh[2][2] = {};

#pragma unroll
    for (int ks = 0; ks < 16; ++ks) {
        const bool lo = (ks < 8);              // compile-time after unroll
        const int kk = (ks & 7) * 32;
        const unsigned short* Ab = lo ? Sb : Hb;
        const unsigned short* Wb = lo ? WS : WH;
        v8s a[2], bR[2], bZ[2], bN[2];
        a[0]  = *(const v8s*)(Ab + offA0 + kk);
        a[1]  = *(const v8s*)(Ab + offA1 + kk);
        bR[0] = *(const v8s*)(Wb + oR0 + kk);
        bR[1] = *(const v8s*)(Wb + oR1 + kk);
        bZ[0] = *(const v8s*)(Wb + oZ0 + kk);
        bZ[1] = *(const v8s*)(Wb + oZ1 + kk);
        bN[0] = *(const v8s*)(Wb + oN0 + kk);
        bN[1] = *(const v8s*)(Wb + oN1 + kk);
#pragma unroll
        for (int fi = 0; fi < 2; fi++)
#pragma unroll
            for (int fj = 0; fj < 2; fj++) {
                aR[fi][fj] = __builtin_amdgcn_mfma_f32_16x16x32_bf16(a[fi], bR[fj], aR[fi][fj], 0, 0, 0);
                aZ[fi][fj] = __builtin_amdgcn_mfma_f32_16x16x32_bf16(a[fi], bZ[fj], aZ[fi][fj], 0, 0, 0);
                if (lo)
                    aNi[fi][fj] = __builtin_amdgcn_mfma_f32_16x16x32_bf16(a[fi], bN[fj], aNi[fi][fj], 0, 0, 0);
                else
                    aNh[fi][fj] = __builtin_amdgcn_mfma_f32_16x16x32_bf16(a[fi], bN[fj], aNh[fi][fj], 0, 0, 0);
            }
    }

    // epilogue: gates in fp32
    const int rbase = (lane >> 4) * 4;
#pragma unroll
    for (int fj = 0; fj < 2; fj++) {
        int col = c0 + fj * 16 + lr;
        float brz_r = b_ih[col] + b_hh[col];
        float brz_z = b_ih[col + 256] + b_hh[col + 256];
        float bi_n = b_ih[col + 512];
        float bh_n = b_hh[col + 512];
#pragma unroll
        for (int fi = 0; fi < 2; fi++)
#pragma unroll
            for (int r = 0; r < 4; r++) {
                int row = n0 + fi * 16 + rbase + r;
                float hold = b2f(Hb[(size_t)row * C + col]);
                float rg = 1.f / (1.f + __expf(-(aR[fi][fj][r] + brz_r)));
                float z  = 1.f / (1.f + __expf(-(aZ[fi][fj][r] + brz_z)));
                float nn = tanhf(aNi[fi][fj][r] + bi_n + rg * (aNh[fi][fj][r] + bh_n));
                float out = (1.f - z) * nn + z * hold;
                Hout[(size_t)row * C + col] = f2b(out);
            }
    }
}

// ---------------------------------------------------------------------------
// mean pool: one block per graph (batch is sorted -> binary search bounds)
// ---------------------------------------------------------------------------
__global__ __launch_bounds__(256) void pool2(const unsigned short* __restrict__ Hb,
                                             const int* __restrict__ batch,
                                             float* __restrict__ g) {
    int b = blockIdx.x, j = threadIdx.x;
    __shared__ int bound[2];
    if (j < 2) {
        int target = b + j;
        int lo = 0, hi = N_NODES;
        while (lo < hi) {
            int mid = (lo + hi) >> 1;
            if (batch[mid] < target) lo = mid + 1; else hi = mid;
        }
        bound[j] = lo;
    }
    __syncthreads();
    int slo = bound[0], shi = bound[1];
    float a0 = 0.f, a1 = 0.f, a2 = 0.f, a3 = 0.f;
    int row = slo;
    for (; row + 3 < shi; row += 4) {
        a0 += b2f(Hb[(size_t)(row + 0) * C + j]);
        a1 += b2f(Hb[(size_t)(row + 1) * C + j]);
        a2 += b2f(Hb[(size_t)(row + 2) * C + j]);
        a3 += b2f(Hb[(size_t)(row + 3) * C + j]);
    }
    for (; row < shi; ++row) a0 += b2f(Hb[(size_t)row * C + j]);
    float acc = (a0 + a1) + (a2 + a3);
    float cnt = (float)(shi - slo);
    g[b * C + j] = acc / fmaxf(cnt, 1.f);
}

__global__ __launch_bounds__(128) void cls_kernel(const float* __restrict__ g,
                                                  const float* __restrict__ W1,
                                                  const float* __restrict__ b1,
                                                  const float* __restrict__ W2,
                                                  const float* __restrict__ b2,
                                                  float* __restrict__ out) {
    int b = blockIdx.x, j = threadIdx.x;
    float acc = b1[j];
    for (int k = 0; k < C; k += 4) {
        float4 gv = *(const float4*)(g + (size_t)b * C + k);
        float4 wv = *(const float4*)(W1 + (size_t)j * C + k);
        acc += gv.x * wv.x + gv.y * wv.y + gv.z * wv.z + gv.w * wv.w;
    }
    float hc = fmaxf(acc, 0.f);
    float v = W2[j] * hc;
    __shared__ float red[128];
    red[j] = v;
    __syncthreads();
    for (int s = 64; s > 0; s >>= 1) {
        if (j < s) red[j] += red[j + s];
        __syncthreads();
    }
    if (j == 0) out[b] = 1.f / (1.f + __expf(-(red[0] + b2[0])));
}

// ---------------------------------------------------------------------------
extern "C" void kernel_launch(void* const* d_in, const int* in_sizes, int n_in,
                              void* d_out, int out_size, void* d_ws, size_t ws_size,
                              hipStream_t stream) {
    const float* x      = (const float*)d_in[0];
    const int*   ei     = (const int*)d_in[1];
    const int*   batch  = (const int*)d_in[2];
    const float* weight = (const float*)d_in[3];
    const float* w_ih   = (const float*)d_in[4];
    const float* w_hh   = (const float*)d_in[5];
    const float* b_ih   = (const float*)d_in[6];
    const float* b_hh   = (const float*)d_in[7];
    const float* W1     = (const float*)d_in[8];
    const float* b1     = (const float*)d_in[9];
    const float* W2     = (const float*)d_in[10];
    const float* b2     = (const float*)d_in[11];
    float* out = (float*)d_out;

    char* ws = (char*)d_ws;
    size_t o = 0;
    auto alloc = [&](size_t bytes) {
        void* p = ws + o;
        o = (o + bytes + 255) & ~(size_t)255;
        return p;
    };
    unsigned short* HbA = (unsigned short*)alloc((size_t)NPAD * C * 2);
    unsigned short* HbB = (unsigned short*)alloc((size_t)NPAD * C * 2);
    unsigned short* Sb  = (unsigned short*)alloc((size_t)NPAD * C * 2);
    unsigned short* WSb = (unsigned short*)alloc((size_t)LAYERS * 768 * C * 2);
    unsigned short* WHb = (unsigned short*)alloc((size_t)768 * C * 2);
    float* g = (float*)alloc((size_t)N_GRAPHS * C * 4);
    int* deg     = (int*)alloc((size_t)N_NODES * 4);
    int* row_ptr = (int*)alloc((size_t)(N_NODES + 1) * 4);
    int* cursor  = (int*)alloc((size_t)N_NODES * 4);
    int* col_src = (int*)alloc((size_t)N_EDGES * 4);

    // weight prep + CSR build
    conv_whh<<<768, 256, 0, stream>>>(w_hh, WHb);
    fuse_ws<<<dim3(12, 4, 6), 256, 0, stream>>>(w_ih, weight, WSb);
    hipMemsetAsync(deg, 0, (size_t)N_NODES * 4, stream);
    count_kernel<<<(N_EDGES + 255) / 256, 256, 0, stream>>>(ei, deg);
    scan_kernel<<<1, 1024, 0, stream>>>(deg, row_ptr, cursor);
    fill_kernel<<<(N_EDGES + 255) / 256, 256, 0, stream>>>(ei, cursor, col_src);

    // h0 = pad(x) -> bf16
    pad_kernel<<<(NPAD * 32) / 256, 256, 0, stream>>>(x, HbA);

    unsigned short* hcur = HbA;
    unsigned short* hnxt = HbB;
    for (int l = 0; l < LAYERS; ++l) {
        gather_bf16<<<(N_NODES + 3) / 4, 256, 0, stream>>>(hcur, row_ptr, col_src, Sb);
        gru_fused<<<NPAD / 64 * 4, 256, 0, stream>>>(Sb, hcur, WSb + (size_t)l * 768 * C, WHb,
                                                     b_ih, b_hh, hnxt);
        unsigned short* t = hcur; hcur = hnxt; hnxt = t;
    }

    pool2<<<N_GRAPHS, 256, 0, stream>>>(hcur, batch, g);
    cls_kernel<<<N_GRAPHS, 128, 0, stream>>>(g, W1, b1, W2, b2, out);
}

// Round 7
// 978.673 us; speedup vs baseline: 7.0311x; 1.6710x over previous
//
#include <hip/hip_runtime.h>
#include <hip/hip_bf16.h>
#include <math.h>

#define N_NODES 50000
#define NPAD    50048            // 391 * 128
#define N_EDGES 300000
#define IN_DIM  128
#define C       256
#define LAYERS  6
#define N_GRAPHS 256

typedef __attribute__((ext_vector_type(8))) short v8s;
typedef __attribute__((ext_vector_type(4))) float v4f;

__device__ __forceinline__ unsigned short f2b(float f) {   // fp32 -> bf16 RNE
    unsigned int u = __float_as_uint(f);
    unsigned int r = (u + 0x7FFFu + ((u >> 16) & 1u)) >> 16;
    return (unsigned short)r;
}
__device__ __forceinline__ float b2f(unsigned short b) {
    return __uint_as_float(((unsigned int)b) << 16);
}

// async global->LDS, 16B per lane. HW: LDS dest = wave-uniform base + lane*16;
// our per-lane dest is linear in lane so intent == HW behavior.
__device__ __forceinline__ void gload16(const unsigned short* g, unsigned short* l) {
    __builtin_amdgcn_global_load_lds(
        (const __attribute__((address_space(1))) unsigned int*)(const void*)g,
        (__attribute__((address_space(3))) unsigned int*)(void*)l, 16, 0, 0);
}

// ---------------------------------------------------------------------------
// CSR build
// ---------------------------------------------------------------------------
__global__ void count_kernel(const int* __restrict__ ei, int* __restrict__ deg) {
    int e = blockIdx.x * blockDim.x + threadIdx.x;
    if (e < N_EDGES) atomicAdd(&deg[ei[N_EDGES + e]], 1);
}

__global__ void scan_kernel(const int* __restrict__ deg, int* __restrict__ row_ptr,
                            int* __restrict__ cursor) {
    __shared__ int buf[1024];
    __shared__ int carry_s;
    int tid = threadIdx.x;
    if (tid == 0) carry_s = 0;
    __syncthreads();
    for (int base = 0; base < N_NODES; base += 1024) {
        int i = base + tid;
        int v = (i < N_NODES) ? deg[i] : 0;
        buf[tid] = v;
        __syncthreads();
        for (int off = 1; off < 1024; off <<= 1) {
            int t = (tid >= off) ? buf[tid - off] : 0;
            __syncthreads();
            buf[tid] += t;
            __syncthreads();
        }
        int excl = buf[tid] - v;
        int carry = carry_s;
        if (i < N_NODES) { row_ptr[i] = carry + excl; cursor[i] = carry + excl; }
        __syncthreads();
        if (tid == 0) carry_s = carry + buf[1023];
        __syncthreads();
    }
    if (tid == 0) row_ptr[N_NODES] = carry_s;
}

__global__ void fill_kernel(const int* __restrict__ ei, int* __restrict__ cursor,
                            int* __restrict__ col_src) {
    int e = blockIdx.x * blockDim.x + threadIdx.x;
    if (e >= N_EDGES) return;
    int d = ei[N_EDGES + e];
    int pos = atomicAdd(&cursor[d], 1);
    col_src[pos] = ei[e];
}

// ---------------------------------------------------------------------------
// weight prep.
//  WH [768][256] = bf16(w_hh)
//  WS [6][768][256]: WS_l = w_l @ Wih^T fold (fp32 math)
// ---------------------------------------------------------------------------
__global__ __launch_bounds__(256) void conv_whh(const float* __restrict__ whh,
                                                unsigned short* __restrict__ WH) {
    int t = blockIdx.x * 256 + threadIdx.x;
    if (t < 768 * 256) WH[t] = f2b(whh[t]);
}

__global__ __launch_bounds__(256) void fuse_ws(const float* __restrict__ wih,
                                               const float* __restrict__ w,
                                               unsigned short* __restrict__ WS) {
    __shared__ float As[16][64];
    __shared__ float Bs[16][64];
    const int j0 = blockIdx.x * 64;
    const int k0 = blockIdx.y * 64;
    const int l  = blockIdx.z;
    const float* wl = w + (size_t)l * C * C;
    const int tid = threadIdx.x;
    const int ty = tid >> 4, tx = tid & 15;
    const int lrow = tid >> 2, lt4 = (tid & 3) * 4;
    float acc[4][4] = {};
    for (int t0 = 0; t0 < C; t0 += 16) {
        float4 a = *(const float4*)(wih + (size_t)(j0 + lrow) * C + t0 + lt4);
        As[lt4 + 0][lrow] = a.x; As[lt4 + 1][lrow] = a.y;
        As[lt4 + 2][lrow] = a.z; As[lt4 + 3][lrow] = a.w;
        float4 b = *(const float4*)(wl + (size_t)(k0 + lrow) * C + t0 + lt4);
        Bs[lt4 + 0][lrow] = b.x; Bs[lt4 + 1][lrow] = b.y;
        Bs[lt4 + 2][lrow] = b.z; Bs[lt4 + 3][lrow] = b.w;
        __syncthreads();
#pragma unroll
        for (int kk = 0; kk < 16; ++kk) {
            float af[4], bf[4];
#pragma unroll
            for (int i = 0; i < 4; i++) { af[i] = As[kk][ty * 4 + i]; bf[i] = Bs[kk][tx * 4 + i]; }
#pragma unroll
            for (int i = 0; i < 4; i++)
#pragma unroll
                for (int j = 0; j < 4; j++) acc[i][j] += af[i] * bf[j];
        }
        __syncthreads();
    }
    unsigned short* outp = WS + (size_t)l * 768 * C;
#pragma unroll
    for (int i = 0; i < 4; i++)
#pragma unroll
        for (int j = 0; j < 4; j++)
            outp[(size_t)(j0 + ty * 4 + i) * C + k0 + tx * 4 + j] = f2b(acc[i][j]);
}

// ---------------------------------------------------------------------------
// pad x [N,128] -> Hb bf16 [NPAD,256]
// ---------------------------------------------------------------------------
__global__ __launch_bounds__(256) void pad_kernel(const float* __restrict__ x,
                                                  unsigned short* __restrict__ Hb) {
    int t = blockIdx.x * 256 + threadIdx.x;
    int node = t >> 5, q = t & 31;
    if (node >= NPAD) return;
    v8s out = {0, 0, 0, 0, 0, 0, 0, 0};
    if (node < N_NODES && q < 16) {
        const float* xp = x + (size_t)node * IN_DIM + q * 8;
        float4 a = *(const float4*)xp;
        float4 b = *(const float4*)(xp + 4);
        out[0] = (short)f2b(a.x); out[1] = (short)f2b(a.y);
        out[2] = (short)f2b(a.z); out[3] = (short)f2b(a.w);
        out[4] = (short)f2b(b.x); out[5] = (short)f2b(b.y);
        out[6] = (short)f2b(b.z); out[7] = (short)f2b(b.w);
    }
    *(v8s*)(Hb + (size_t)node * C + q * 8) = out;
}

// ---------------------------------------------------------------------------
// S[d] = sum_{e: dst==d} h[src_e]
// ---------------------------------------------------------------------------
__global__ __launch_bounds__(256) void gather_bf16(const unsigned short* __restrict__ Hb,
                                                   const int* __restrict__ row_ptr,
                                                   const int* __restrict__ col_src,
                                                   unsigned short* __restrict__ Sb) {
    int wave = threadIdx.x >> 6, lane = threadIdx.x & 63;
    int node = blockIdx.x * 4 + wave;
    if (node >= N_NODES) return;
    int beg = row_ptr[node], end = row_ptr[node + 1];
    float a0 = 0.f, a1 = 0.f, a2 = 0.f, a3 = 0.f;
    for (int p = beg; p < end; ++p) {
        int s = col_src[p];
        uint2 raw = *(const uint2*)(Hb + (size_t)s * C + lane * 4);
        a0 += __uint_as_float((raw.x & 0xFFFFu) << 16);
        a1 += __uint_as_float(raw.x & 0xFFFF0000u);
        a2 += __uint_as_float((raw.y & 0xFFFFu) << 16);
        a3 += __uint_as_float(raw.y & 0xFFFF0000u);
    }
    uint2 out;
    out.x = (unsigned int)f2b(a0) | ((unsigned int)f2b(a1) << 16);
    out.y = (unsigned int)f2b(a2) | ((unsigned int)f2b(a3) << 16);
    *(uint2*)(Sb + (size_t)node * C + lane * 4) = out;
}

// ---------------------------------------------------------------------------
// Fused GRU, LDS-staged 2-phase pipeline (m97-style, BK=32 so LDS rows are
// 64B -> only 2-way bank aliasing, no swizzle needed).
// Block: 256 thr = 4 waves (2x2); tile 128 rows x 64 out-cols x {R,Z,N}.
// Wave: 64 rows x 32 cols. K = 512 virtual (S-half then H-half), 16 steps.
// ---------------------------------------------------------------------------
__global__ __launch_bounds__(256, 2) void gru_fused(const unsigned short* __restrict__ Sb,
                                                    const unsigned short* __restrict__ Hb,
                                                    const unsigned short* __restrict__ WS,
                                                    const unsigned short* __restrict__ WH,
                                                    const float* __restrict__ b_ih,
                                                    const float* __restrict__ b_hh,
                                                    unsigned short* __restrict__ Hout) {
    __shared__ unsigned short AsL[2][128 * 32];   // [buf][row*32 + k]   8KB each
    __shared__ unsigned short BsL[2][192 * 32];   // [buf][vrow*32 + k] 12KB each

    const int tid = threadIdx.x;
    const int lane = tid & 63, wid = tid >> 6;
    const int wr = wid >> 1, wc = wid & 1;        // wave grid 2x2
    const int gr0 = blockIdx.x * 128;             // 391 M-blocks
    const int c0 = blockIdx.y * 64;               // 4 col-blocks
    const int lr = lane & 15;
    const int kg = (lane >> 4) * 8;

    // staging lane mapping: LDS byte = instr*1024 + lane*16
    const int srow = lane >> 2;                   // 0..15 within 16-row group
    const int schunk = (lane & 3) * 8;            // bf16 col offset, 16B chunks

    v4f aR[4][2] = {}, aZ[4][2] = {}, aNi[4][2] = {}, aNh[4][2] = {};

    // ---- staging: issue all gload_lds for K-step t into buffer b ----
    auto stage = [&](int b, int t) {
        const bool lo2 = (t < 8);
        const unsigned short* Asrc = lo2 ? Sb : Hb;
        const unsigned short* Wsrc = lo2 ? WS : WH;
        const int kc = (t & 7) * 32;
        unsigned short* Ab = AsL[b];
        unsigned short* Bb = BsL[b];
        // A: 8 wave-instrs total, this wave does 2
#pragma unroll
        for (int ii = 0; ii < 2; ++ii) {
            int i = wid * 2 + ii;
            int row = i * 16 + srow;
            gload16(Asrc + (size_t)(gr0 + row) * C + kc + schunk,
                    Ab + row * 32 + schunk);
        }
        // B: 12 wave-instrs total, this wave does 3. vrow: [R 0..63|Z 64..127|N 128..191]
#pragma unroll
        for (int jj = 0; jj < 3; ++jj) {
            int j = wid * 3 + jj;
            int vrow = j * 16 + srow;
            int g = vrow >> 6, cc = vrow & 63;
            gload16(Wsrc + (size_t)(g * 256 + c0 + cc) * C + kc + schunk,
                    Bb + vrow * 32 + schunk);
        }
    };

    // ---- compute: ds_read fragments from buffer b, MFMA for step t ----
    auto compute = [&](int b, bool lo2) {
        const unsigned short* Ab = AsL[b];
        const unsigned short* Bb = BsL[b];
        v8s a[4], bR[2], bZ[2], bN[2];
#pragma unroll
        for (int fi = 0; fi < 4; fi++)
            a[fi] = *(const v8s*)(Ab + (wr * 64 + fi * 16 + lr) * 32 + kg);
#pragma unroll
        for (int fj = 0; fj < 2; fj++) {
            int brow = wc * 32 + fj * 16 + lr;
            bR[fj] = *(const v8s*)(Bb + brow * 32 + kg);
            bZ[fj] = *(const v8s*)(Bb + (brow + 64) * 32 + kg);
            bN[fj] = *(const v8s*)(Bb + (brow + 128) * 32 + kg);
        }
#pragma unroll
        for (int fi = 0; fi < 4; fi++)
#pragma unroll
            for (int fj = 0; fj < 2; fj++) {
                aR[fi][fj] = __builtin_amdgcn_mfma_f32_16x16x32_bf16(a[fi], bR[fj], aR[fi][fj], 0, 0, 0);
                aZ[fi][fj] = __builtin_amdgcn_mfma_f32_16x16x32_bf16(a[fi], bZ[fj], aZ[fi][fj], 0, 0, 0);
                if (lo2)
                    aNi[fi][fj] = __builtin_amdgcn_mfma_f32_16x16x32_bf16(a[fi], bN[fj], aNi[fi][fj], 0, 0, 0);
                else
                    aNh[fi][fj] = __builtin_amdgcn_mfma_f32_16x16x32_bf16(a[fi], bN[fj], aNh[fi][fj], 0, 0, 0);
            }
    };

    stage(0, 0);
    __syncthreads();                 // drains vmcnt -> buf0 ready
#pragma unroll
    for (int t = 0; t < 16; ++t) {
        if (t < 15) stage((t + 1) & 1, t + 1);   // prefetch next tile (in flight during compute)
        compute(t & 1, t < 8);
        __syncthreads();             // drains stage(t+1) + protects buf reuse
    }

    // ---- epilogue: gates in fp32 ----
    const int rbase = (lane >> 4) * 4;
#pragma unroll
    for (int fj = 0; fj < 2; fj++) {
        int col = c0 + wc * 32 + fj * 16 + lr;
        float brz_r = b_ih[col] + b_hh[col];
        float brz_z = b_ih[col + 256] + b_hh[col + 256];
        float bi_n = b_ih[col + 512];
        float bh_n = b_hh[col + 512];
#pragma unroll
        for (int fi = 0; fi < 4; fi++)
#pragma unroll
            for (int r = 0; r < 4; r++) {
                int row = gr0 + wr * 64 + fi * 16 + rbase + r;
                float hold = b2f(Hb[(size_t)row * C + col]);
                float rg = 1.f / (1.f + __expf(-(aR[fi][fj][r] + brz_r)));
                float z  = 1.f / (1.f + __expf(-(aZ[fi][fj][r] + brz_z)));
                float nn = tanhf(aNi[fi][fj][r] + bi_n + rg * (aNh[fi][fj][r] + bh_n));
                float outv = (1.f - z) * nn + z * hold;
                Hout[(size_t)row * C + col] = f2b(outv);
            }
    }
}

// ---------------------------------------------------------------------------
// mean pool + classifier
// ---------------------------------------------------------------------------
__global__ __launch_bounds__(256) void pool2(const unsigned short* __restrict__ Hb,
                                             const int* __restrict__ batch,
                                             float* __restrict__ g) {
    int b = blockIdx.x, j = threadIdx.x;
    __shared__ int bound[2];
    if (j < 2) {
        int target = b + j;
        int lo = 0, hi = N_NODES;
        while (lo < hi) {
            int mid = (lo + hi) >> 1;
            if (batch[mid] < target) lo = mid + 1; else hi = mid;
        }
        bound[j] = lo;
    }
    __syncthreads();
    int slo = bound[0], shi = bound[1];
    float a0 = 0.f, a1 = 0.f, a2 = 0.f, a3 = 0.f;
    int row = slo;
    for (; row + 3 < shi; row += 4) {
        a0 += b2f(Hb[(size_t)(row + 0) * C + j]);
        a1 += b2f(Hb[(size_t)(row + 1) * C + j]);
        a2 += b2f(Hb[(size_t)(row + 2) * C + j]);
        a3 += b2f(Hb[(size_t)(row + 3) * C + j]);
    }
    for (; row < shi; ++row) a0 += b2f(Hb[(size_t)row * C + j]);
    float acc = (a0 + a1) + (a2 + a3);
    float cnt = (float)(shi - slo);
    g[b * C + j] = acc / fmaxf(cnt, 1.f);
}

__global__ __launch_bounds__(128) void cls_kernel(const float* __restrict__ g,
                                                  const float* __restrict__ W1,
                                                  const float* __restrict__ b1,
                                                  const float* __restrict__ W2,
                                                  const float* __restrict__ b2,
                                                  float* __restrict__ out) {
    int b = blockIdx.x, j = threadIdx.x;
    float acc = b1[j];
    for (int k = 0; k < C; k += 4) {
        float4 gv = *(const float4*)(g + (size_t)b * C + k);
        float4 wv = *(const float4*)(W1 + (size_t)j * C + k);
        acc += gv.x * wv.x + gv.y * wv.y + gv.z * wv.z + gv.w * wv.w;
    }
    float hc = fmaxf(acc, 0.f);
    float v = W2[j] * hc;
    __shared__ float red[128];
    red[j] = v;
    __syncthreads();
    for (int s = 64; s > 0; s >>= 1) {
        if (j < s) red[j] += red[j + s];
        __syncthreads();
    }
    if (j == 0) out[b] = 1.f / (1.f + __expf(-(red[0] + b2[0])));
}

// ---------------------------------------------------------------------------
extern "C" void kernel_launch(void* const* d_in, const int* in_sizes, int n_in,
                              void* d_out, int out_size, void* d_ws, size_t ws_size,
                              hipStream_t stream) {
    const float* x      = (const float*)d_in[0];
    const int*   ei     = (const int*)d_in[1];
    const int*   batch  = (const int*)d_in[2];
    const float* weight = (const float*)d_in[3];
    const float* w_ih   = (const float*)d_in[4];
    const float* w_hh   = (const float*)d_in[5];
    const float* b_ih   = (const float*)d_in[6];
    const float* b_hh   = (const float*)d_in[7];
    const float* W1     = (const float*)d_in[8];
    const float* b1     = (const float*)d_in[9];
    const float* W2     = (const float*)d_in[10];
    const float* b2     = (const float*)d_in[11];
    float* out = (float*)d_out;

    char* ws = (char*)d_ws;
    size_t o = 0;
    auto alloc = [&](size_t bytes) {
        void* p = ws + o;
        o = (o + bytes + 255) & ~(size_t)255;
        return p;
    };
    unsigned short* HbA = (unsigned short*)alloc((size_t)NPAD * C * 2);
    unsigned short* HbB = (unsigned short*)alloc((size_t)NPAD * C * 2);
    unsigned short* Sb  = (unsigned short*)alloc((size_t)NPAD * C * 2);
    unsigned short* WSb = (unsigned short*)alloc((size_t)LAYERS * 768 * C * 2);
    unsigned short* WHb = (unsigned short*)alloc((size_t)768 * C * 2);
    float* g = (float*)alloc((size_t)N_GRAPHS * C * 4);
    int* deg     = (int*)alloc((size_t)N_NODES * 4);
    int* row_ptr = (int*)alloc((size_t)(N_NODES + 1) * 4);
    int* cursor  = (int*)alloc((size_t)N_NODES * 4);
    int* col_src = (int*)alloc((size_t)N_EDGES * 4);

    // weight prep + CSR build
    conv_whh<<<768, 256, 0, stream>>>(w_hh, WHb);
    fuse_ws<<<dim3(12, 4, 6), 256, 0, stream>>>(w_ih, weight, WSb);
    hipMemsetAsync(deg, 0, (size_t)N_NODES * 4, stream);
    count_kernel<<<(N_EDGES + 255) / 256, 256, 0, stream>>>(ei, deg);
    scan_kernel<<<1, 1024, 0, stream>>>(deg, row_ptr, cursor);
    fill_kernel<<<(N_EDGES + 255) / 256, 256, 0, stream>>>(ei, cursor, col_src);

    // h0 = pad(x) -> bf16
    pad_kernel<<<(NPAD * 32) / 256, 256, 0, stream>>>(x, HbA);

    unsigned short* hcur = HbA;
    unsigned short* hnxt = HbB;
    for (int l = 0; l < LAYERS; ++l) {
        gather_bf16<<<(N_NODES + 3) / 4, 256, 0, stream>>>(hcur, row_ptr, col_src, Sb);
        gru_fused<<<dim3(NPAD / 128, 4), 256, 0, stream>>>(Sb, hcur, WSb + (size_t)l * 768 * C, WHb,
                                                           b_ih, b_hh, hnxt);
        unsigned short* t = hcur; hcur = hnxt; hnxt = t;
    }

    pool2<<<N_GRAPHS, 256, 0, stream>>>(hcur, batch, g);
    cls_kernel<<<N_GRAPHS, 128, 0, stream>>>(g, W1, b1, W2, b2, out);
}

// Round 8
// 817.029 us; speedup vs baseline: 8.4221x; 1.1978x over previous
//
#include <hip/hip_runtime.h>
#include <hip/hip_bf16.h>
#include <math.h>

#define N_NODES 50000
#define NPAD    50048            // 391 * 128
#define N_EDGES 300000
#define IN_DIM  128
#define C       256
#define LAYERS  6
#define N_GRAPHS 256
#define SCAN_B  49               // ceil(N_NODES / 1024)

typedef __attribute__((ext_vector_type(8))) short v8s;
typedef __attribute__((ext_vector_type(4))) float v4f;

__device__ __forceinline__ unsigned short f2b(float f) {   // fp32 -> bf16 RNE
    unsigned int u = __float_as_uint(f);
    unsigned int r = (u + 0x7FFFu + ((u >> 16) & 1u)) >> 16;
    return (unsigned short)r;
}
__device__ __forceinline__ float b2f(unsigned short b) {
    return __uint_as_float(((unsigned int)b) << 16);
}

// async global->LDS, 16B per lane. LDS dest must be linear (base + lane*16);
// per-lane GLOBAL source is allowed -> swizzle lives on the source side.
__device__ __forceinline__ void gload16(const unsigned short* g, unsigned short* l) {
    __builtin_amdgcn_global_load_lds(
        (const __attribute__((address_space(1))) unsigned int*)(const void*)g,
        (__attribute__((address_space(3))) unsigned int*)(void*)l, 16, 0, 0);
}

// ---------------------------------------------------------------------------
// CSR build: count -> hierarchical scan (A/B/C) -> fill
// ---------------------------------------------------------------------------
__global__ void count_kernel(const int* __restrict__ ei, int* __restrict__ deg) {
    int e = blockIdx.x * blockDim.x + threadIdx.x;
    if (e < N_EDGES) atomicAdd(&deg[ei[N_EDGES + e]], 1);
}

__global__ __launch_bounds__(1024) void scanA(const int* __restrict__ deg,
                                              int* __restrict__ pre,
                                              int* __restrict__ bsum) {
    __shared__ int buf[1024];
    int b = blockIdx.x, tid = threadIdx.x;
    int i = b * 1024 + tid;
    int v = (i < N_NODES) ? deg[i] : 0;
    buf[tid] = v;
    __syncthreads();
    for (int off = 1; off < 1024; off <<= 1) {
        int t = (tid >= off) ? buf[tid - off] : 0;
        __syncthreads();
        buf[tid] += t;
        __syncthreads();
    }
    if (i < N_NODES) pre[i] = buf[tid] - v;   // exclusive within block
    if (tid == 1023) bsum[b] = buf[1023];
}

__global__ void scanB(int* __restrict__ bsum) {
    if (threadIdx.x == 0 && blockIdx.x == 0) {
        int acc = 0;
        for (int b = 0; b < SCAN_B; ++b) { int t = bsum[b]; bsum[b] = acc; acc += t; }
    }
}

__global__ __launch_bounds__(256) void scanC(const int* __restrict__ pre,
                                             const int* __restrict__ bsum,
                                             int* __restrict__ row_ptr,
                                             int* __restrict__ cursor) {
    int i = blockIdx.x * 256 + threadIdx.x;
    if (i < N_NODES) {
        int v = pre[i] + bsum[i >> 10];
        row_ptr[i] = v;
        cursor[i] = v;
    }
    if (i == N_NODES) row_ptr[N_NODES] = N_EDGES;
}

__global__ void fill_kernel(const int* __restrict__ ei, int* __restrict__ cursor,
                            int* __restrict__ col_src) {
    int e = blockIdx.x * blockDim.x + threadIdx.x;
    if (e >= N_EDGES) return;
    int d = ei[N_EDGES + e];
    int pos = atomicAdd(&cursor[d], 1);
    col_src[pos] = ei[e];
}

// ---------------------------------------------------------------------------
// weight prep.
//  WH [768][256] = bf16(w_hh)
//  WS [6][768][256]: WS_l = w_l @ Wih^T fold (fp32 math)
// ---------------------------------------------------------------------------
__global__ __launch_bounds__(256) void conv_whh(const float* __restrict__ whh,
                                                unsigned short* __restrict__ WH) {
    int t = blockIdx.x * 256 + threadIdx.x;
    if (t < 768 * 256) WH[t] = f2b(whh[t]);
}

__global__ __launch_bounds__(256) void fuse_ws(const float* __restrict__ wih,
                                               const float* __restrict__ w,
                                               unsigned short* __restrict__ WS) {
    __shared__ float As[16][64];
    __shared__ float Bs[16][64];
    const int j0 = blockIdx.x * 64;
    const int k0 = blockIdx.y * 64;
    const int l  = blockIdx.z;
    const float* wl = w + (size_t)l * C * C;
    const int tid = threadIdx.x;
    const int ty = tid >> 4, tx = tid & 15;
    const int lrow = tid >> 2, lt4 = (tid & 3) * 4;
    float acc[4][4] = {};
    for (int t0 = 0; t0 < C; t0 += 16) {
        float4 a = *(const float4*)(wih + (size_t)(j0 + lrow) * C + t0 + lt4);
        As[lt4 + 0][lrow] = a.x; As[lt4 + 1][lrow] = a.y;
        As[lt4 + 2][lrow] = a.z; As[lt4 + 3][lrow] = a.w;
        float4 b = *(const float4*)(wl + (size_t)(k0 + lrow) * C + t0 + lt4);
        Bs[lt4 + 0][lrow] = b.x; Bs[lt4 + 1][lrow] = b.y;
        Bs[lt4 + 2][lrow] = b.z; Bs[lt4 + 3][lrow] = b.w;
        __syncthreads();
#pragma unroll
        for (int kk = 0; kk < 16; ++kk) {
            float af[4], bf[4];
#pragma unroll
            for (int i = 0; i < 4; i++) { af[i] = As[kk][ty * 4 + i]; bf[i] = Bs[kk][tx * 4 + i]; }
#pragma unroll
            for (int i = 0; i < 4; i++)
#pragma unroll
                for (int j = 0; j < 4; j++) acc[i][j] += af[i] * bf[j];
        }
        __syncthreads();
    }
    unsigned short* outp = WS + (size_t)l * 768 * C;
#pragma unroll
    for (int i = 0; i < 4; i++)
#pragma unroll
        for (int j = 0; j < 4; j++)
            outp[(size_t)(j0 + ty * 4 + i) * C + k0 + tx * 4 + j] = f2b(acc[i][j]);
}

// ---------------------------------------------------------------------------
// pad x [N,128] -> Hb bf16 [NPAD,256]
// ---------------------------------------------------------------------------
__global__ __launch_bounds__(256) void pad_kernel(const float* __restrict__ x,
                                                  unsigned short* __restrict__ Hb) {
    int t = blockIdx.x * 256 + threadIdx.x;
    int node = t >> 5, q = t & 31;
    if (node >= NPAD) return;
    v8s out = {0, 0, 0, 0, 0, 0, 0, 0};
    if (node < N_NODES && q < 16) {
        const float* xp = x + (size_t)node * IN_DIM + q * 8;
        float4 a = *(const float4*)xp;
        float4 b = *(const float4*)(xp + 4);
        out[0] = (short)f2b(a.x); out[1] = (short)f2b(a.y);
        out[2] = (short)f2b(a.z); out[3] = (short)f2b(a.w);
        out[4] = (short)f2b(b.x); out[5] = (short)f2b(b.y);
        out[6] = (short)f2b(b.z); out[7] = (short)f2b(b.w);
    }
    *(v8s*)(Hb + (size_t)node * C + q * 8) = out;
}

// ---------------------------------------------------------------------------
// S[d] = sum_{e: dst==d} h[src_e]  — 4-edge unroll, 4 independent row loads
// in flight per wave (latency hiding; edges avg degree 6).
// ---------------------------------------------------------------------------
__global__ __launch_bounds__(256) void gather_bf16(const unsigned short* __restrict__ Hb,
                                                   const int* __restrict__ row_ptr,
                                                   const int* __restrict__ col_src,
                                                   unsigned short* __restrict__ Sb) {
    int wave = threadIdx.x >> 6, lane = threadIdx.x & 63;
    int node = blockIdx.x * 4 + wave;
    if (node >= N_NODES) return;
    int beg = row_ptr[node], end = row_ptr[node + 1];
    float a0 = 0.f, a1 = 0.f, a2 = 0.f, a3 = 0.f;
    const unsigned short* hp = Hb + lane * 4;

    auto accum = [&](uint2 raw) {
        a0 += __uint_as_float((raw.x & 0xFFFFu) << 16);
        a1 += __uint_as_float(raw.x & 0xFFFF0000u);
        a2 += __uint_as_float((raw.y & 0xFFFFu) << 16);
        a3 += __uint_as_float(raw.y & 0xFFFF0000u);
    };

    int p = beg;
    for (; p + 4 <= end; p += 4) {
        int s0 = col_src[p + 0], s1 = col_src[p + 1];
        int s2 = col_src[p + 2], s3 = col_src[p + 3];
        uint2 r0 = *(const uint2*)(hp + (size_t)s0 * C);
        uint2 r1 = *(const uint2*)(hp + (size_t)s1 * C);
        uint2 r2 = *(const uint2*)(hp + (size_t)s2 * C);
        uint2 r3 = *(const uint2*)(hp + (size_t)s3 * C);
        accum(r0); accum(r1); accum(r2); accum(r3);
    }
    for (; p < end; ++p) {
        int s = col_src[p];
        accum(*(const uint2*)(hp + (size_t)s * C));
    }
    uint2 out;
    out.x = (unsigned int)f2b(a0) | ((unsigned int)f2b(a1) << 16);
    out.y = (unsigned int)f2b(a2) | ((unsigned int)f2b(a3) << 16);
    *(uint2*)(Sb + (size_t)node * C + lane * 4) = out;
}

// ---------------------------------------------------------------------------
// Fused GRU, LDS-staged 2-phase pipeline with XOR bank swizzle.
// LDS rows are 32 bf16 = 64B = 4 chunks of 16B. Physical chunk p of row r
// holds logical chunk p ^ ((r>>1)&3): write side pre-swizzles the GLOBAL
// source (LDS dest stays linear for global_load_lds); read side applies the
// same XOR. Spreads each 16-lane ds_read phase over all 8 bank slots.
// ---------------------------------------------------------------------------
__global__ __launch_bounds__(256, 2) void gru_fused(const unsigned short* __restrict__ Sb,
                                                    const unsigned short* __restrict__ Hb,
                                                    const unsigned short* __restrict__ WS,
                                                    const unsigned short* __restrict__ WH,
                                                    const float* __restrict__ b_ih,
                                                    const float* __restrict__ b_hh,
                                                    unsigned short* __restrict__ Hout) {
    __shared__ unsigned short AsL[2][128 * 32];   // [buf][row*32 + k]   8KB each
    __shared__ unsigned short BsL[2][192 * 32];   // [buf][vrow*32 + k] 12KB each

    const int tid = threadIdx.x;
    const int lane = tid & 63, wid = tid >> 6;
    const int wr = wid >> 1, wc = wid & 1;        // wave grid 2x2
    const int gr0 = blockIdx.x * 128;             // 391 M-blocks
    const int c0 = blockIdx.y * 64;               // 4 col-blocks
    const int lr = lane & 15;

    // read-side swizzled chunk offset (elements): phys = (lane>>4) ^ ((lr>>1)&3)
    const int kg = (((lane >> 4) ^ ((lr >> 1) & 3)) & 3) * 8;

    // staging lane mapping: LDS byte = instr*1024 + lane*16 (linear);
    // global source chunk = (lane&3) ^ ((srow>>1)&3), srow = lane>>2
    const int srow = lane >> 2;
    const int schunk = (((lane & 3) ^ ((lane >> 3) & 3)) & 3) * 8;

    v4f aR[4][2] = {}, aZ[4][2] = {}, aNi[4][2] = {}, aNh[4][2] = {};

    auto stage = [&](int b, int t) {
        const bool lo2 = (t < 8);
        const unsigned short* Asrc = lo2 ? Sb : Hb;
        const unsigned short* Wsrc = lo2 ? WS : WH;
        const int kc = (t & 7) * 32;
        unsigned short* Ab = AsL[b];
        unsigned short* Bb = BsL[b];
#pragma unroll
        for (int ii = 0; ii < 2; ++ii) {
            int i = wid * 2 + ii;
            int row = i * 16 + srow;
            gload16(Asrc + (size_t)(gr0 + row) * C + kc + schunk,
                    Ab + row * 32 + (lane & 3) * 8);
        }
#pragma unroll
        for (int jj = 0; jj < 3; ++jj) {
            int j = wid * 3 + jj;
            int vrow = j * 16 + srow;
            int g = vrow >> 6, cc = vrow & 63;
            gload16(Wsrc + (size_t)(g * 256 + c0 + cc) * C + kc + schunk,
                    Bb + vrow * 32 + (lane & 3) * 8);
        }
    };

    auto compute = [&](int b, bool lo2) {
        const unsigned short* Ab = AsL[b];
        const unsigned short* Bb = BsL[b];
        v8s a[4], bR[2], bZ[2], bN[2];
#pragma unroll
        for (int fi = 0; fi < 4; fi++)
            a[fi] = *(const v8s*)(Ab + (wr * 64 + fi * 16 + lr) * 32 + kg);
#pragma unroll
        for (int fj = 0; fj < 2; fj++) {
            int brow = wc * 32 + fj * 16 + lr;
            bR[fj] = *(const v8s*)(Bb + brow * 32 + kg);
            bZ[fj] = *(const v8s*)(Bb + (brow + 64) * 32 + kg);
            bN[fj] = *(const v8s*)(Bb + (brow + 128) * 32 + kg);
        }
#pragma unroll
        for (int fi = 0; fi < 4; fi++)
#pragma unroll
            for (int fj = 0; fj < 2; fj++) {
                aR[fi][fj] = __builtin_amdgcn_mfma_f32_16x16x32_bf16(a[fi], bR[fj], aR[fi][fj], 0, 0, 0);
                aZ[fi][fj] = __builtin_amdgcn_mfma_f32_16x16x32_bf16(a[fi], bZ[fj], aZ[fi][fj], 0, 0, 0);
                if (lo2)
                    aNi[fi][fj] = __builtin_amdgcn_mfma_f32_16x16x32_bf16(a[fi], bN[fj], aNi[fi][fj], 0, 0, 0);
                else
                    aNh[fi][fj] = __builtin_amdgcn_mfma_f32_16x16x32_bf16(a[fi], bN[fj], aNh[fi][fj], 0, 0, 0);
            }
    };

    stage(0, 0);
    __syncthreads();
#pragma unroll
    for (int t = 0; t < 16; ++t) {
        if (t < 15) stage((t + 1) & 1, t + 1);   // async prefetch overlaps compute
        compute(t & 1, t < 8);
        __syncthreads();
    }

    // ---- epilogue: gates in fp32 ----
    const int rbase = (lane >> 4) * 4;
#pragma unroll
    for (int fj = 0; fj < 2; fj++) {
        int col = c0 + wc * 32 + fj * 16 + lr;
        float brz_r = b_ih[col] + b_hh[col];
        float brz_z = b_ih[col + 256] + b_hh[col + 256];
        float bi_n = b_ih[col + 512];
        float bh_n = b_hh[col + 512];
#pragma unroll
        for (int fi = 0; fi < 4; fi++)
#pragma unroll
            for (int r = 0; r < 4; r++) {
                int row = gr0 + wr * 64 + fi * 16 + rbase + r;
                float hold = b2f(Hb[(size_t)row * C + col]);
                float rg = 1.f / (1.f + __expf(-(aR[fi][fj][r] + brz_r)));
                float z  = 1.f / (1.f + __expf(-(aZ[fi][fj][r] + brz_z)));
                float nn = tanhf(aNi[fi][fj][r] + bi_n + rg * (aNh[fi][fj][r] + bh_n));
                float outv = (1.f - z) * nn + z * hold;
                Hout[(size_t)row * C + col] = f2b(outv);
            }
    }
}

// ---------------------------------------------------------------------------
// mean pool + classifier
// ---------------------------------------------------------------------------
__global__ __launch_bounds__(256) void pool2(const unsigned short* __restrict__ Hb,
                                             const int* __restrict__ batch,
                                             float* __restrict__ g) {
    int b = blockIdx.x, j = threadIdx.x;
    __shared__ int bound[2];
    if (j < 2) {
        int target = b + j;
        int lo = 0, hi = N_NODES;
        while (lo < hi) {
            int mid = (lo + hi) >> 1;
            if (batch[mid] < target) lo = mid + 1; else hi = mid;
        }
        bound[j] = lo;
    }
    __syncthreads();
    int slo = bound[0], shi = bound[1];
    float a0 = 0.f, a1 = 0.f, a2 = 0.f, a3 = 0.f;
    int row = slo;
    for (; row + 3 < shi; row += 4) {
        a0 += b2f(Hb[(size_t)(row + 0) * C + j]);
        a1 += b2f(Hb[(size_t)(row + 1) * C + j]);
        a2 += b2f(Hb[(size_t)(row + 2) * C + j]);
        a3 += b2f(Hb[(size_t)(row + 3) * C + j]);
    }
    for (; row < shi; ++row) a0 += b2f(Hb[(size_t)row * C + j]);
    float acc = (a0 + a1) + (a2 + a3);
    float cnt = (float)(shi - slo);
    g[b * C + j] = acc / fmaxf(cnt, 1.f);
}

__global__ __launch_bounds__(128) void cls_kernel(const float* __restrict__ g,
                                                  const float* __restrict__ W1,
                                                  const float* __restrict__ b1,
                                                  const float* __restrict__ W2,
                                                  const float* __restrict__ b2,
                                                  float* __restrict__ out) {
    int b = blockIdx.x, j = threadIdx.x;
    float acc = b1[j];
    for (int k = 0; k < C; k += 4) {
        float4 gv = *(const float4*)(g + (size_t)b * C + k);
        float4 wv = *(const float4*)(W1 + (size_t)j * C + k);
        acc += gv.x * wv.x + gv.y * wv.y + gv.z * wv.z + gv.w * wv.w;
    }
    float hc = fmaxf(acc, 0.f);
    float v = W2[j] * hc;
    __shared__ float red[128];
    red[j] = v;
    __syncthreads();
    for (int s = 64; s > 0; s >>= 1) {
        if (j < s) red[j] += red[j + s];
        __syncthreads();
    }
    if (j == 0) out[b] = 1.f / (1.f + __expf(-(red[0] + b2[0])));
}

// ---------------------------------------------------------------------------
extern "C" void kernel_launch(void* const* d_in, const int* in_sizes, int n_in,
                              void* d_out, int out_size, void* d_ws, size_t ws_size,
                              hipStream_t stream) {
    const float* x      = (const float*)d_in[0];
    const int*   ei     = (const int*)d_in[1];
    const int*   batch  = (const int*)d_in[2];
    const float* weight = (const float*)d_in[3];
    const float* w_ih   = (const float*)d_in[4];
    const float* w_hh   = (const float*)d_in[5];
    const float* b_ih   = (const float*)d_in[6];
    const float* b_hh   = (const float*)d_in[7];
    const float* W1     = (const float*)d_in[8];
    const float* b1     = (const float*)d_in[9];
    const float* W2     = (const float*)d_in[10];
    const float* b2     = (const float*)d_in[11];
    float* out = (float*)d_out;

    char* ws = (char*)d_ws;
    size_t o = 0;
    auto alloc = [&](size_t bytes) {
        void* p = ws + o;
        o = (o + bytes + 255) & ~(size_t)255;
        return p;
    };
    unsigned short* HbA = (unsigned short*)alloc((size_t)NPAD * C * 2);
    unsigned short* HbB = (unsigned short*)alloc((size_t)NPAD * C * 2);
    unsigned short* Sb  = (unsigned short*)alloc((size_t)NPAD * C * 2);
    unsigned short* WSb = (unsigned short*)alloc((size_t)LAYERS * 768 * C * 2);
    unsigned short* WHb = (unsigned short*)alloc((size_t)768 * C * 2);
    float* g = (float*)alloc((size_t)N_GRAPHS * C * 4);
    int* deg     = (int*)alloc((size_t)N_NODES * 4);
    int* pre     = (int*)alloc((size_t)N_NODES * 4);
    int* bsum    = (int*)alloc((size_t)64 * 4);
    int* row_ptr = (int*)alloc((size_t)(N_NODES + 1) * 4);
    int* cursor  = (int*)alloc((size_t)N_NODES * 4);
    int* col_src = (int*)alloc((size_t)N_EDGES * 4);

    // weight prep + CSR build
    conv_whh<<<768, 256, 0, stream>>>(w_hh, WHb);
    fuse_ws<<<dim3(12, 4, 6), 256, 0, stream>>>(w_ih, weight, WSb);
    hipMemsetAsync(deg, 0, (size_t)N_NODES * 4, stream);
    count_kernel<<<(N_EDGES + 255) / 256, 256, 0, stream>>>(ei, deg);
    scanA<<<SCAN_B, 1024, 0, stream>>>(deg, pre, bsum);
    scanB<<<1, 64, 0, stream>>>(bsum);
    scanC<<<(N_NODES + 256) / 256, 256, 0, stream>>>(pre, bsum, row_ptr, cursor);
    fill_kernel<<<(N_EDGES + 255) / 256, 256, 0, stream>>>(ei, cursor, col_src);

    // h0 = pad(x) -> bf16
    pad_kernel<<<(NPAD * 32) / 256, 256, 0, stream>>>(x, HbA);

    unsigned short* hcur = HbA;
    unsigned short* hnxt = HbB;
    for (int l = 0; l < LAYERS; ++l) {
        gather_bf16<<<(N_NODES + 3) / 4, 256, 0, stream>>>(hcur, row_ptr, col_src, Sb);
        gru_fused<<<dim3(NPAD / 128, 4), 256, 0, stream>>>(Sb, hcur, WSb + (size_t)l * 768 * C, WHb,
                                                           b_ih, b_hh, hnxt);
        unsigned short* t = hcur; hcur = hnxt; hnxt = t;
    }

    pool2<<<N_GRAPHS, 256, 0, stream>>>(hcur, batch, g);
    cls_kernel<<<N_GRAPHS, 128, 0, stream>>>(g, W1, b1, W2, b2, out);
}

// Round 10
// 779.881 us; speedup vs baseline: 8.8233x; 1.0476x over previous
//
#include <hip/hip_runtime.h>
#include <hip/hip_bf16.h>
#include <math.h>

#define N_NODES 50000
#define NPAD    50048            // 391 * 128
#define N_EDGES 300000
#define IN_DIM  128
#define C       256
#define LAYERS  6
#define N_GRAPHS 256
#define SCAN_B  49               // ceil(N_NODES / 1024)

typedef __attribute__((ext_vector_type(8))) short v8s;
typedef __attribute__((ext_vector_type(4))) float v4f;

__device__ __forceinline__ unsigned short f2b(float f) {   // fp32 -> bf16 RNE
    unsigned int u = __float_as_uint(f);
    unsigned int r = (u + 0x7FFFu + ((u >> 16) & 1u)) >> 16;
    return (unsigned short)r;
}
__device__ __forceinline__ float b2f(unsigned short b) {
    return __uint_as_float(((unsigned int)b) << 16);
}

// async global->LDS, 16B per lane. LDS dest must be linear (base + lane*16);
// per-lane GLOBAL source is allowed -> swizzle lives on the source side.
__device__ __forceinline__ void gload16(const unsigned short* g, unsigned short* l) {
    __builtin_amdgcn_global_load_lds(
        (const __attribute__((address_space(1))) unsigned int*)(const void*)g,
        (__attribute__((address_space(3))) unsigned int*)(void*)l, 16, 0, 0);
}

// ---------------------------------------------------------------------------
// CSR build: count -> hierarchical scan (A/B/C) -> fill
// ---------------------------------------------------------------------------
__global__ void count_kernel(const int* __restrict__ ei, int* __restrict__ deg) {
    int e = blockIdx.x * blockDim.x + threadIdx.x;
    if (e < N_EDGES) atomicAdd(&deg[ei[N_EDGES + e]], 1);
}

__global__ __launch_bounds__(1024) void scanA(const int* __restrict__ deg,
                                              int* __restrict__ pre,
                                              int* __restrict__ bsum) {
    __shared__ int buf[1024];
    int b = blockIdx.x, tid = threadIdx.x;
    int i = b * 1024 + tid;
    int v = (i < N_NODES) ? deg[i] : 0;
    buf[tid] = v;
    __syncthreads();
    for (int off = 1; off < 1024; off <<= 1) {
        int t = (tid >= off) ? buf[tid - off] : 0;
        __syncthreads();
        buf[tid] += t;
        __syncthreads();
    }
    if (i < N_NODES) pre[i] = buf[tid] - v;   // exclusive within block
    if (tid == 1023) bsum[b] = buf[1023];
}

__global__ void scanB(int* __restrict__ bsum) {
    if (threadIdx.x == 0 && blockIdx.x == 0) {
        int acc = 0;
        for (int b = 0; b < SCAN_B; ++b) { int t = bsum[b]; bsum[b] = acc; acc += t; }
    }
}

__global__ __launch_bounds__(256) void scanC(const int* __restrict__ pre,
                                             const int* __restrict__ bsum,
                                             int* __restrict__ row_ptr,
                                             int* __restrict__ cursor) {
    int i = blockIdx.x * 256 + threadIdx.x;
    if (i < N_NODES) {
        int v = pre[i] + bsum[i >> 10];
        row_ptr[i] = v;
        cursor[i] = v;
    }
    if (i == N_NODES) row_ptr[N_NODES] = N_EDGES;
}

__global__ void fill_kernel(const int* __restrict__ ei, int* __restrict__ cursor,
                            int* __restrict__ col_src) {
    int e = blockIdx.x * blockDim.x + threadIdx.x;
    if (e >= N_EDGES) return;
    int d = ei[N_EDGES + e];
    int pos = atomicAdd(&cursor[d], 1);
    col_src[pos] = ei[e];
}

// ---------------------------------------------------------------------------
// weight prep.
//  WH [768][256] = bf16(w_hh)
//  WS [6][768][256]: WS_l = w_l @ Wih^T fold (fp32 math)
// ---------------------------------------------------------------------------
__global__ __launch_bounds__(256) void conv_whh(const float* __restrict__ whh,
                                                unsigned short* __restrict__ WH) {
    int t = blockIdx.x * 256 + threadIdx.x;
    if (t < 768 * 256) WH[t] = f2b(whh[t]);
}

__global__ __launch_bounds__(256) void fuse_ws(const float* __restrict__ wih,
                                               const float* __restrict__ w,
                                               unsigned short* __restrict__ WS) {
    __shared__ float As[16][64];
    __shared__ float Bs[16][64];
    const int j0 = blockIdx.x * 64;
    const int k0 = blockIdx.y * 64;
    const int l  = blockIdx.z;
    const float* wl = w + (size_t)l * C * C;
    const int tid = threadIdx.x;
    const int ty = tid >> 4, tx = tid & 15;
    const int lrow = tid >> 2, lt4 = (tid & 3) * 4;
    float acc[4][4] = {};
    for (int t0 = 0; t0 < C; t0 += 16) {
        float4 a = *(const float4*)(wih + (size_t)(j0 + lrow) * C + t0 + lt4);
        As[lt4 + 0][lrow] = a.x; As[lt4 + 1][lrow] = a.y;
        As[lt4 + 2][lrow] = a.z; As[lt4 + 3][lrow] = a.w;
        float4 b = *(const float4*)(wl + (size_t)(k0 + lrow) * C + t0 + lt4);
        Bs[lt4 + 0][lrow] = b.x; Bs[lt4 + 1][lrow] = b.y;
        Bs[lt4 + 2][lrow] = b.z; Bs[lt4 + 3][lrow] = b.w;
        __syncthreads();
#pragma unroll
        for (int kk = 0; kk < 16; ++kk) {
            float af[4], bf[4];
#pragma unroll
            for (int i = 0; i < 4; i++) { af[i] = As[kk][ty * 4 + i]; bf[i] = Bs[kk][tx * 4 + i]; }
#pragma unroll
            for (int i = 0; i < 4; i++)
#pragma unroll
                for (int j = 0; j < 4; j++) acc[i][j] += af[i] * bf[j];
        }
        __syncthreads();
    }
    unsigned short* outp = WS + (size_t)l * 768 * C;
#pragma unroll
    for (int i = 0; i < 4; i++)
#pragma unroll
        for (int j = 0; j < 4; j++)
            outp[(size_t)(j0 + ty * 4 + i) * C + k0 + tx * 4 + j] = f2b(acc[i][j]);
}

// ---------------------------------------------------------------------------
// pad x [N,128] -> Hb bf16 [NPAD,256]
// ---------------------------------------------------------------------------
__global__ __launch_bounds__(256) void pad_kernel(const float* __restrict__ x,
                                                  unsigned short* __restrict__ Hb) {
    int t = blockIdx.x * 256 + threadIdx.x;
    int node = t >> 5, q = t & 31;
    if (node >= NPAD) return;
    v8s out = {0, 0, 0, 0, 0, 0, 0, 0};
    if (node < N_NODES && q < 16) {
        const float* xp = x + (size_t)node * IN_DIM + q * 8;
        float4 a = *(const float4*)xp;
        float4 b = *(const float4*)(xp + 4);
        out[0] = (short)f2b(a.x); out[1] = (short)f2b(a.y);
        out[2] = (short)f2b(a.z); out[3] = (short)f2b(a.w);
        out[4] = (short)f2b(b.x); out[5] = (short)f2b(b.y);
        out[6] = (short)f2b(b.z); out[7] = (short)f2b(b.w);
    }
    *(v8s*)(Hb + (size_t)node * C + q * 8) = out;
}

// ---------------------------------------------------------------------------
// S[d] = sum_{e: dst==d} h[src_e]  — 4-edge unroll (4 independent row loads)
// ---------------------------------------------------------------------------
__global__ __launch_bounds__(256) void gather_bf16(const unsigned short* __restrict__ Hb,
                                                   const int* __restrict__ row_ptr,
                                                   const int* __restrict__ col_src,
                                                   unsigned short* __restrict__ Sb) {
    int wave = threadIdx.x >> 6, lane = threadIdx.x & 63;
    int node = blockIdx.x * 4 + wave;
    if (node >= N_NODES) return;
    int beg = row_ptr[node], end = row_ptr[node + 1];
    float a0 = 0.f, a1 = 0.f, a2 = 0.f, a3 = 0.f;
    const unsigned short* hp = Hb + lane * 4;

    auto accum = [&](uint2 raw) {
        a0 += __uint_as_float((raw.x & 0xFFFFu) << 16);
        a1 += __uint_as_float(raw.x & 0xFFFF0000u);
        a2 += __uint_as_float((raw.y & 0xFFFFu) << 16);
        a3 += __uint_as_float(raw.y & 0xFFFF0000u);
    };

    int p = beg;
    for (; p + 4 <= end; p += 4) {
        int s0 = col_src[p + 0], s1 = col_src[p + 1];
        int s2 = col_src[p + 2], s3 = col_src[p + 3];
        uint2 r0 = *(const uint2*)(hp + (size_t)s0 * C);
        uint2 r1 = *(const uint2*)(hp + (size_t)s1 * C);
        uint2 r2 = *(const uint2*)(hp + (size_t)s2 * C);
        uint2 r3 = *(const uint2*)(hp + (size_t)s3 * C);
        accum(r0); accum(r1); accum(r2); accum(r3);
    }
    for (; p < end; ++p) {
        int s = col_src[p];
        accum(*(const uint2*)(hp + (size_t)s * C));
    }
    uint2 out;
    out.x = (unsigned int)f2b(a0) | ((unsigned int)f2b(a1) << 16);
    out.y = (unsigned int)f2b(a2) | ((unsigned int)f2b(a3) << 16);
    *(uint2*)(Sb + (size_t)node * C + lane * 4) = out;
}

// ---------------------------------------------------------------------------
// Fused GRU, LDS-staged double-buffer with COUNTED vmcnt (T4) + bijective
// XCD swizzle (T1, m204) + XOR bank swizzle (T2, kept from round 8).
// Per K-step each wave issues 5 global_load_lds for step t+1, then waits
// vmcnt(5) (stage t done, stage t+1 still in flight), raw s_barrier, MFMA,
// raw s_barrier. Loads are never drained to 0 inside the loop.
// ---------------------------------------------------------------------------
__global__ __launch_bounds__(256, 2) void gru_fused(const unsigned short* __restrict__ Sb,
                                                    const unsigned short* __restrict__ Hb,
                                                    const unsigned short* __restrict__ WS,
                                                    const unsigned short* __restrict__ WH,
                                                    const float* __restrict__ b_ih,
                                                    const float* __restrict__ b_hh,
                                                    unsigned short* __restrict__ Hout) {
    __shared__ unsigned short AsL[2][128 * 32];   // [buf][row*32 + k]   8KB each
    __shared__ unsigned short BsL[2][192 * 32];   // [buf][vrow*32 + k] 12KB each

    const int tid = threadIdx.x;
    const int lane = tid & 63, wid = tid >> 6;
    const int wr = wid >> 1, wc = wid & 1;        // wave grid 2x2

    // bijective XCD swizzle over 1564 blocks (8 XCDs; 1564 = 8*195 + 4).
    // Logical L: col-block fast (L&3) -> the 4 blocks sharing A-rows are
    // dispatch-adjacent on one XCD -> A re-reads hit that XCD's L2.
    const int p = blockIdx.x;
    const int xcd = p & 7;
    const int q = 1564 >> 3, r8 = 1564 & 7;       // 195, 4
    const int base = (xcd < r8) ? xcd * (q + 1) : r8 * (q + 1) + (xcd - r8) * q;
    const int L = base + (p >> 3);
    const int gr0 = (L >> 2) * 128;               // 391 row-blocks
    const int c0 = (L & 3) * 64;                  // 4 col-blocks
    const int lr = lane & 15;

    // read-side swizzled chunk offset: phys = (lane>>4) ^ ((lr>>1)&3)
    const int kg = (((lane >> 4) ^ ((lr >> 1) & 3)) & 3) * 8;

    // staging: LDS dest linear (lane*16); global source chunk xor-swizzled
    const int srow = lane >> 2;
    const int schunk = (((lane & 3) ^ ((lane >> 3) & 3)) & 3) * 8;

    v4f aR[4][2] = {}, aZ[4][2] = {}, aNi[4][2] = {}, aNh[4][2] = {};

    auto stage = [&](int b, int t) {
        const bool lo2 = (t < 8);
        const unsigned short* Asrc = lo2 ? Sb : Hb;
        const unsigned short* Wsrc = lo2 ? WS : WH;
        const int kc = (t & 7) * 32;
        unsigned short* Ab = AsL[b];
        unsigned short* Bb = BsL[b];
#pragma unroll
        for (int ii = 0; ii < 2; ++ii) {
            int i = wid * 2 + ii;
            int row = i * 16 + srow;
            gload16(Asrc + (size_t)(gr0 + row) * C + kc + schunk,
                    Ab + row * 32 + (lane & 3) * 8);
        }
#pragma unroll
        for (int jj = 0; jj < 3; ++jj) {
            int j = wid * 3 + jj;
            int vrow = j * 16 + srow;
            int g = vrow >> 6, cc = vrow & 63;
            gload16(Wsrc + (size_t)(g * 256 + c0 + cc) * C + kc + schunk,
                    Bb + vrow * 32 + (lane & 3) * 8);
        }
    };

    auto compute = [&](int b, bool lo2) {
        const unsigned short* Ab = AsL[b];
        const unsigned short* Bb = BsL[b];
        v8s a[4], bR[2], bZ[2], bN[2];
#pragma unroll
        for (int fi = 0; fi < 4; fi++)
            a[fi] = *(const v8s*)(Ab + (wr * 64 + fi * 16 + lr) * 32 + kg);
#pragma unroll
        for (int fj = 0; fj < 2; fj++) {
            int brow = wc * 32 + fj * 16 + lr;
            bR[fj] = *(const v8s*)(Bb + brow * 32 + kg);
            bZ[fj] = *(const v8s*)(Bb + (brow + 64) * 32 + kg);
            bN[fj] = *(const v8s*)(Bb + (brow + 128) * 32 + kg);
        }
#pragma unroll
        for (int fi = 0; fi < 4; fi++)
#pragma unroll
            for (int fj = 0; fj < 2; fj++) {
                aR[fi][fj] = __builtin_amdgcn_mfma_f32_16x16x32_bf16(a[fi], bR[fj], aR[fi][fj], 0, 0, 0);
                aZ[fi][fj] = __builtin_amdgcn_mfma_f32_16x16x32_bf16(a[fi], bZ[fj], aZ[fi][fj], 0, 0, 0);
                if (lo2)
                    aNi[fi][fj] = __builtin_amdgcn_mfma_f32_16x16x32_bf16(a[fi], bN[fj], aNi[fi][fj], 0, 0, 0);
                else
                    aNh[fi][fj] = __builtin_amdgcn_mfma_f32_16x16x32_bf16(a[fi], bN[fj], aNh[fi][fj], 0, 0, 0);
            }
    };

    stage(0, 0);
#pragma unroll
    for (int t = 0; t < 16; ++t) {
        if (t < 15) {
            stage((t + 1) & 1, t + 1);     // +5 in flight (never drained below)
            asm volatile("s_waitcnt vmcnt(5)" ::: "memory");   // stage(t) done
        } else {
            asm volatile("s_waitcnt vmcnt(0)" ::: "memory");   // tail drain
        }
        __builtin_amdgcn_sched_barrier(0);
        __builtin_amdgcn_s_barrier();      // all waves: buf[t] fully written
        __builtin_amdgcn_sched_barrier(0);
        compute(t & 1, t < 8);             // plain LDS reads; compiler lgkmcnt
        __builtin_amdgcn_sched_barrier(0);
        __builtin_amdgcn_s_barrier();      // all waves done reading buf[t]
        __builtin_amdgcn_sched_barrier(0);
    }

    // ---- epilogue: gates in fp32 ----
    const int rbase = (lane >> 4) * 4;
#pragma unroll
    for (int fj = 0; fj < 2; fj++) {
        int col = c0 + wc * 32 + fj * 16 + lr;
        float brz_r = b_ih[col] + b_hh[col];
        float brz_z = b_ih[col + 256] + b_hh[col + 256];
        float bi_n = b_ih[col + 512];
        float bh_n = b_hh[col + 512];
#pragma unroll
        for (int fi = 0; fi < 4; fi++)
#pragma unroll
            for (int r = 0; r < 4; r++) {
                int row = gr0 + wr * 64 + fi * 16 + rbase + r;
                float hold = b2f(Hb[(size_t)row * C + col]);
                float rg = 1.f / (1.f + __expf(-(aR[fi][fj][r] + brz_r)));
                float z  = 1.f / (1.f + __expf(-(aZ[fi][fj][r] + brz_z)));
                float nn = tanhf(aNi[fi][fj][r] + bi_n + rg * (aNh[fi][fj][r] + bh_n));
                float outv = (1.f - z) * nn + z * hold;
                Hout[(size_t)row * C + col] = f2b(outv);
            }
    }
}

// ---------------------------------------------------------------------------
// mean pool + classifier
// ---------------------------------------------------------------------------
__global__ __launch_bounds__(256) void pool2(const unsigned short* __restrict__ Hb,
                                             const int* __restrict__ batch,
                                             float* __restrict__ g) {
    int b = blockIdx.x, j = threadIdx.x;
    __shared__ int bound[2];
    if (j < 2) {
        int target = b + j;
        int lo = 0, hi = N_NODES;
        while (lo < hi) {
            int mid = (lo + hi) >> 1;
            if (batch[mid] < target) lo = mid + 1; else hi = mid;
        }
        bound[j] = lo;
    }
    __syncthreads();
    int slo = bound[0], shi = bound[1];
    float a0 = 0.f, a1 = 0.f, a2 = 0.f, a3 = 0.f;
    int row = slo;
    for (; row + 3 < shi; row += 4) {
        a0 += b2f(Hb[(size_t)(row + 0) * C + j]);
        a1 += b2f(Hb[(size_t)(row + 1) * C + j]);
        a2 += b2f(Hb[(size_t)(row + 2) * C + j]);
        a3 += b2f(Hb[(size_t)(row + 3) * C + j]);
    }
    for (; row < shi; ++row) a0 += b2f(Hb[(size_t)row * C + j]);
    float acc = (a0 + a1) + (a2 + a3);
    float cnt = (float)(shi - slo);
    g[b * C + j] = acc / fmaxf(cnt, 1.f);
}

__global__ __launch_bounds__(128) void cls_kernel(const float* __restrict__ g,
                                                  const float* __restrict__ W1,
                                                  const float* __restrict__ b1,
                                                  const float* __restrict__ W2,
                                                  const float* __restrict__ b2,
                                                  float* __restrict__ out) {
    int b = blockIdx.x, j = threadIdx.x;
    float acc = b1[j];
    for (int k = 0; k < C; k += 4) {
        float4 gv = *(const float4*)(g + (size_t)b * C + k);
        float4 wv = *(const float4*)(W1 + (size_t)j * C + k);
        acc += gv.x * wv.x + gv.y * wv.y + gv.z * wv.z + gv.w * wv.w;
    }
    float hc = fmaxf(acc, 0.f);
    float v = W2[j] * hc;
    __shared__ float red[128];
    red[j] = v;
    __syncthreads();
    for (int s = 64; s > 0; s >>= 1) {
        if (j < s) red[j] += red[j + s];
        __syncthreads();
    }
    if (j == 0) out[b] = 1.f / (1.f + __expf(-(red[0] + b2[0])));
}

// ---------------------------------------------------------------------------
extern "C" void kernel_launch(void* const* d_in, const int* in_sizes, int n_in,
                              void* d_out, int out_size, void* d_ws, size_t ws_size,
                              hipStream_t stream) {
    const float* x      = (const float*)d_in[0];
    const int*   ei     = (const int*)d_in[1];
    const int*   batch  = (const int*)d_in[2];
    const float* weight = (const float*)d_in[3];
    const float* w_ih   = (const float*)d_in[4];
    const float* w_hh   = (const float*)d_in[5];
    const float* b_ih   = (const float*)d_in[6];
    const float* b_hh   = (const float*)d_in[7];
    const float* W1     = (const float*)d_in[8];
    const float* b1     = (const float*)d_in[9];
    const float* W2     = (const float*)d_in[10];
    const float* b2     = (const float*)d_in[11];
    float* out = (float*)d_out;

    char* ws = (char*)d_ws;
    size_t o = 0;
    auto alloc = [&](size_t bytes) {
        void* p = ws + o;
        o = (o + bytes + 255) & ~(size_t)255;
        return p;
    };
    unsigned short* HbA = (unsigned short*)alloc((size_t)NPAD * C * 2);
    unsigned short* HbB = (unsigned short*)alloc((size_t)NPAD * C * 2);
    unsigned short* Sb  = (unsigned short*)alloc((size_t)NPAD * C * 2);
    unsigned short* WSb = (unsigned short*)alloc((size_t)LAYERS * 768 * C * 2);
    unsigned short* WHb = (unsigned short*)alloc((size_t)768 * C * 2);
    float* g = (float*)alloc((size_t)N_GRAPHS * C * 4);
    int* deg     = (int*)alloc((size_t)N_NODES * 4);
    int* pre     = (int*)alloc((size_t)N_NODES * 4);
    int* bsum    = (int*)alloc((size_t)64 * 4);
    int* row_ptr = (int*)alloc((size_t)(N_NODES + 1) * 4);
    int* cursor  = (int*)alloc((size_t)N_NODES * 4);
    int* col_src = (int*)alloc((size_t)N_EDGES * 4);

    // weight prep + CSR build
    conv_whh<<<768, 256, 0, stream>>>(w_hh, WHb);
    fuse_ws<<<dim3(12, 4, 6), 256, 0, stream>>>(w_ih, weight, WSb);
    hipMemsetAsync(deg, 0, (size_t)N_NODES * 4, stream);
    count_kernel<<<(N_EDGES + 255) / 256, 256, 0, stream>>>(ei, deg);
    scanA<<<SCAN_B, 1024, 0, stream>>>(deg, pre, bsum);
    scanB<<<1, 64, 0, stream>>>(bsum);
    scanC<<<(N_NODES + 256) / 256, 256, 0, stream>>>(pre, bsum, row_ptr, cursor);
    fill_kernel<<<(N_EDGES + 255) / 256, 256, 0, stream>>>(ei, cursor, col_src);

    // h0 = pad(x) -> bf16
    pad_kernel<<<(NPAD * 32) / 256, 256, 0, stream>>>(x, HbA);

    unsigned short* hcur = HbA;
    unsigned short* hnxt = HbB;
    for (int l = 0; l < LAYERS; ++l) {
        gather_bf16<<<(N_NODES + 3) / 4, 256, 0, stream>>>(hcur, row_ptr, col_src, Sb);
        gru_fused<<<1564, 256, 0, stream>>>(Sb, hcur, WSb + (size_t)l * 768 * C, WHb,
                                            b_ih, b_hh, hnxt);
        unsigned short* t = hcur; hcur = hnxt; hnxt = t;
    }

    pool2<<<N_GRAPHS, 256, 0, stream>>>(hcur, batch, g);
    cls_kernel<<<N_GRAPHS, 128, 0, stream>>>(g, W1, b1, W2, b2, out);
}